// Round 10
// baseline (1097.241 us; speedup 1.0000x reference)
//
#include <hip/hip_runtime.h>
#include <hip/hip_bf16.h>
#include <cstdint>

#define B_ 16
#define N_ 4096
#define CPTS_ 64
#define M_ 1024
#define K_ 32
#define MF_TOT 2097152   // B_*M_*128 pooled outputs

using ushort8 = __attribute__((ext_vector_type(8))) unsigned short;

static __device__ __forceinline__ unsigned f2bf(float x){
  unsigned u = __float_as_uint(x);
  return (u + 0x7fffu + ((u >> 16) & 1u)) >> 16;   // RTNE
}
static __device__ __forceinline__ float bf2f(unsigned short u){
  return __uint_as_float(((unsigned)u) << 16);
}

// DPP max step: v = max(v, dpp_shift(v)). Values are >= 0 so 0-fill is identity.
#define DPPMAX(v, ctrl)                                                        \
  do {                                                                         \
    int _t = __builtin_amdgcn_update_dpp(0, __float_as_int(v), (ctrl), 0xf,    \
                                         0xf, true);                           \
    (v) = fmaxf((v), __int_as_float(_t));                                      \
  } while (0)

// One distance update, all indices compile-time constant (named float4 comps).
#define STEP(MD, PX, PY, PZ, C, J)                                             \
  { float dx = PX.C - cx, dy = PY.C - cy, dz = PZ.C - cz;                      \
    float d = dx * dx; d = d + dy * dy; d = d + dz * dz;                       \
    float nm = fminf(MD.C, d); MD.C = nm;                                      \
    if (nm > bv){ bv = nm; bj = (J); } }
#define STEP4(MD, PX, PY, PZ, J0)                                              \
  STEP(MD, PX, PY, PZ, x, J0)                                                  \
  STEP(MD, PX, PY, PZ, y, (J0) + 1)                                            \
  STEP(MD, PX, PY, PZ, z, (J0) + 2)                                            \
  STEP(MD, PX, PY, PZ, w, (J0) + 3)

// ---------------- FPS: R7 body, exchange via ds_max_u64 atomic --------------
// 3-phase slot rotation: at iter m winners atomicMax slot[m%3] pre-barrier;
// post-barrier all read slot[m%3], tid0 resets slot[(m-1)%3] (its readers
// finished before THIS barrier; next atomics to it happen after the NEXT
// barrier) -> every hazard window is barrier-separated.
__global__ __launch_bounds__(512, 1) void fps_kernel(const float* __restrict__ xyz,
                                                     float* __restrict__ newxyz){
#pragma clang fp contract(off)
  __shared__ float xs[N_], ys[N_], zs[N_];
  __shared__ int inds_s[M_];
  __shared__ unsigned long long slot[3];
  const int b = blockIdx.x, tid = threadIdx.x;
  const int lane = tid & 63;
  const float* xb = xyz + (size_t)b * N_ * 3;
  if (tid < 3) slot[tid] = 0ull;
  for (int i = tid; i < N_ * 3; i += 512){
    float v = xb[i];
    int n = i / 3, c = i - n * 3;
    if (c == 0) xs[n] = v; else if (c == 1) ys[n] = v; else zs[n] = v;
  }
  __syncthreads();
  // per-lane points: n = tid*8 + j  (wave w owns [w*512, w*512+512))
  const float4 px0 = *reinterpret_cast<const float4*>(&xs[tid * 8 + 0]);
  const float4 px1 = *reinterpret_cast<const float4*>(&xs[tid * 8 + 4]);
  const float4 py0 = *reinterpret_cast<const float4*>(&ys[tid * 8 + 0]);
  const float4 py1 = *reinterpret_cast<const float4*>(&ys[tid * 8 + 4]);
  const float4 pz0 = *reinterpret_cast<const float4*>(&zs[tid * 8 + 0]);
  const float4 pz1 = *reinterpret_cast<const float4*>(&zs[tid * 8 + 4]);
  float4 md0 = make_float4(1e10f, 1e10f, 1e10f, 1e10f);
  float4 md1 = md0;
  int far = 0;
  int s3 = 0, r3 = 2;
  float cx = xs[0], cy = ys[0], cz = zs[0];
  for (int m = 0; m < M_; ++m){
    if (tid == 0) inds_s[m] = far;
    float bv = -1.0f; int bj = 0;
    STEP4(md0, px0, py0, pz0, 0)
    STEP4(md1, px1, py1, pz1, 4)
    // in-wave max via DPP (VALU, no LDS): result in lane 63
    float wm = bv;
    DPPMAX(wm, 0x111);  // row_shr:1
    DPPMAX(wm, 0x112);  // row_shr:2
    DPPMAX(wm, 0x114);  // row_shr:4
    DPPMAX(wm, 0x118);  // row_shr:8
    DPPMAX(wm, 0x142);  // row_bcast:15
    DPPMAX(wm, 0x143);  // row_bcast:31
    const float wmax = __int_as_float(
        __builtin_amdgcn_readlane(__float_as_int(wm), 63));
    // lowest tied lane = smallest n (lane ascending == n ascending per wave)
    unsigned long long tied = __ballot(bv == wmax);
    const int winlane = (int)__builtin_ctzll(tied);
    if (lane == winlane){
      int wn = tid * 8 + bj;
      unsigned long long pk = ((unsigned long long)__float_as_uint(wmax) << 32)
                            | (unsigned)(4095 - wn);   // (4095-n): smaller n wins tie
      atomicMax(&slot[s3], pk);
    }
    __syncthreads();
    unsigned long long p0 = slot[s3];
    if (tid == 0) slot[r3] = 0ull;
    far = 4095 - (int)(p0 & 0xffffffffu);
    cx = xs[far]; cy = ys[far]; cz = zs[far];   // broadcast LDS reads
    s3 = (s3 == 2) ? 0 : s3 + 1;
    r3 = (r3 == 2) ? 0 : r3 + 1;
  }
  __syncthreads();
  for (int t = tid; t < M_; t += 512){
    int id = inds_s[t];
    size_t o = ((size_t)b * M_ + t) * 3;
    newxyz[o] = xs[id]; newxyz[o + 1] = ys[id]; newxyz[o + 2] = zs[id];
  }
}

// ---------------- phi: per-point layer-0 matmul (no gather) -----------------
// phi0[p] = W0 . [xyz[p]; points[p]]  (512 blocks x 128 points)
__global__ __launch_bounds__(256) void phi_kernel(const float* __restrict__ xyz,
                                                  const float* __restrict__ points,
                                                  const float* __restrict__ W,
                                                  float* __restrict__ phi){
  __shared__ __align__(16) float Wt[67][64];
  __shared__ __align__(16) float ft[67][128];
  const int tid = threadIdx.x, blk = blockIdx.x;
  const int p0 = blk * 128;                 // global point id (batch-contiguous)
  for (int i = tid; i < 67 * 64; i += 256){
    int o = i / 67, c = i - o * 67;
    Wt[c][o] = W[i];
  }
  const int sl = tid >> 1, half = tid & 1;
  const int p = p0 + sl;
  const float* ps = points + (size_t)p * CPTS_ + half * 32;
  #pragma unroll
  for (int j = 0; j < 8; ++j){
    float4 v = *reinterpret_cast<const float4*>(ps + j * 4);
    int c = 3 + half * 32 + j * 4;
    ft[c][sl] = v.x; ft[c + 1][sl] = v.y; ft[c + 2][sl] = v.z; ft[c + 3][sl] = v.w;
  }
  if (half == 0){
    const float* xp = xyz + (size_t)p * 3;
    ft[0][sl] = xp[0]; ft[1][sl] = xp[1]; ft[2][sl] = xp[2];   // raw xyz, no centering
  }
  __syncthreads();
  const int sg = tid & 31, og = tid >> 5;
  float acc[4][8];
  #pragma unroll
  for (int i = 0; i < 4; ++i)
    #pragma unroll
    for (int o = 0; o < 8; ++o) acc[i][o] = 0.0f;
  #pragma unroll 2
  for (int c = 0; c < 67; ++c){
    float4 f = *reinterpret_cast<const float4*>(&ft[c][sg * 4]);
    float4 w0 = *reinterpret_cast<const float4*>(&Wt[c][og * 8]);
    float4 w1 = *reinterpret_cast<const float4*>(&Wt[c][og * 8 + 4]);
    const float fv[4] = {f.x, f.y, f.z, f.w};
    #pragma unroll
    for (int i = 0; i < 4; ++i){
      acc[i][0] += fv[i] * w0.x; acc[i][1] += fv[i] * w0.y;
      acc[i][2] += fv[i] * w0.z; acc[i][3] += fv[i] * w0.w;
      acc[i][4] += fv[i] * w1.x; acc[i][5] += fv[i] * w1.y;
      acc[i][6] += fv[i] * w1.z; acc[i][7] += fv[i] * w1.w;
    }
  }
  #pragma unroll
  for (int i = 0; i < 4; ++i){
    float* dst = phi + (size_t)(p0 + sg * 4 + i) * 64 + og * 8;
    *reinterpret_cast<float4*>(dst)     = make_float4(acc[i][0], acc[i][1], acc[i][2], acc[i][3]);
    *reinterpret_cast<float4*>(dst + 4) = make_float4(acc[i][4], acc[i][5], acc[i][6], acc[i][7]);
  }
}

// ---------------- Ball query (blocks 0..4095) + psi (blocks 4096..4159) -----
// psi0[m] = W0a . new_xyz[m]  (first 3 input channels of W0)
__global__ __launch_bounds__(256) void ballq_psi_kernel(const float* __restrict__ xyz,
                                                        const float* __restrict__ newxyz,
                                                        int* __restrict__ gi,
                                                        float* __restrict__ gif,
                                                        const float* __restrict__ W0,
                                                        float* __restrict__ psi){
  if (blockIdx.x >= 4096){
    const int mi = (blockIdx.x - 4096) * 256 + threadIdx.x;   // 0..16383
    const float x = newxyz[(size_t)mi * 3];
    const float y = newxyz[(size_t)mi * 3 + 1];
    const float z = newxyz[(size_t)mi * 3 + 2];
    float* dst = psi + (size_t)mi * 64;
    #pragma unroll
    for (int o4 = 0; o4 < 16; ++o4){
      float v[4];
      #pragma unroll
      for (int e = 0; e < 4; ++e){
        int o = o4 * 4 + e;
        v[e] = fmaf(z, W0[o * 67 + 2], fmaf(y, W0[o * 67 + 1], x * W0[o * 67]));
      }
      *reinterpret_cast<float4*>(dst + o4 * 4) = make_float4(v[0], v[1], v[2], v[3]);
    }
    return;
  }
  const int gw = (blockIdx.x * 256 + threadIdx.x) >> 6;
  const int lane = threadIdx.x & 63;
  const int b = gw >> 10, m = gw & 1023;
  const float* xb = xyz + (size_t)b * N_ * 3;
  const size_t no = (size_t)b * M_ + m;
  const float cx = newxyz[no * 3], cy = newxyz[no * 3 + 1], cz = newxyz[no * 3 + 2];
  const float sm = fmaf(cz, cz, fmaf(cy, cy, cx * cx));
  int total = 0, first_idx = 0; bool havef = false;
  int*   gd = gi  + no * K_;
  float* fd = gif + no * K_;
  for (int ch = 0; ch < 64 && total < K_; ++ch){
    const int n = ch * 64 + lane;
    const float x = xb[n * 3], y = xb[n * 3 + 1], z = xb[n * 3 + 2];
    const float sn = fmaf(z, z, fmaf(y, y, x * x));
    const float dt = fmaf(z, cz, fmaf(y, cy, x * cx));
    float d2 = (sm + sn) - 2.0f * dt;                 // ref: |a|^2+|b|^2-2ab
    float dist = sqrtf(fmaxf(d2, 0.0f));
    bool pred = !(dist > 0.2f);
    unsigned long long mask = __ballot(pred);
    if (!havef && mask){ havef = true; first_idx = ch * 64 + (int)__builtin_ctzll(mask); }
    if (pred){
      int rank = total + (int)__popcll(mask & ((1ull << lane) - 1ull));
      if (rank < K_){ gd[rank] = n; fd[rank] = (float)n; }
    }
    total += (int)__popcll(mask);
  }
  if (total < K_ && lane >= total && lane < K_){ gd[lane] = first_idx; fd[lane] = (float)first_idx; }
}

// ---------------- stats0: BN0 sums over gathered (phi - psi) ----------------
__global__ __launch_bounds__(256) void stats0_kernel(const float* __restrict__ phi,
                                                     const float* __restrict__ psi,
                                                     const int* __restrict__ gi,
                                                     float* __restrict__ part){
  __shared__ int gidx[128];
  __shared__ float psm[4][64];
  const int tid = threadIdx.x, blk = blockIdx.x;
  const size_t s0 = (size_t)blk * 128;
  const int b  = (int)(s0 >> 15);
  const int m0 = ((int)(s0 & 32767)) >> 5;
  if (tid < 128) gidx[tid] = gi[(size_t)b * 32768 + (size_t)m0 * K_ + tid];
  psm[tid >> 6][tid & 63] =
      psi[((size_t)b * M_ + m0 + (tid >> 6)) * 64 + (tid & 63)];
  __syncthreads();
  const int sg = tid & 31, og = tid >> 5;
  const int mi = sg >> 3;
  float sv[8], sq[8];
  #pragma unroll
  for (int o = 0; o < 8; ++o){ sv[o] = 0.f; sq[o] = 0.f; }
  #pragma unroll
  for (int i = 0; i < 4; ++i){
    const int g = gidx[sg * 4 + i];
    const float* gp = phi + ((size_t)b * N_ + g) * 64 + og * 8;
    float4 a0 = *reinterpret_cast<const float4*>(gp);
    float4 a1 = *reinterpret_cast<const float4*>(gp + 4);
    const float pv[8] = {a0.x, a0.y, a0.z, a0.w, a1.x, a1.y, a1.z, a1.w};
    #pragma unroll
    for (int o = 0; o < 8; ++o){
      float v = pv[o] - psm[mi][og * 8 + o];
      sv[o] += v; sq[o] += v * v;
    }
  }
  #pragma unroll
  for (int off = 1; off < 32; off <<= 1){
    #pragma unroll
    for (int o = 0; o < 8; ++o){
      sv[o] += __shfl_xor(sv[o], off);
      sq[o] += __shfl_xor(sq[o], off);
    }
  }
  if (sg == 0){
    #pragma unroll
    for (int o = 0; o < 8; ++o){
      int ch = og * 8 + o;
      part[(size_t)(ch * 2) * 4096 + blk]     = sv[o];
      part[(size_t)(ch * 2 + 1) * 4096 + blk] = sq[o];
    }
  }
}

// ---------------- MLP pass ---------------------------------------------------
// MIN_: 1 = read h_in (bf16) + BN + ReLU;  3 = gather (phi - psi) + BN0 + ReLU
// MOUT_: 0 = store h (bf16) + partial stats
//        4 = partial stats + raw-h max/min over K (f32) -> out (mx | mn)
template<int CIN, int COUT, int MIN_, int MOUT_>
__global__ __launch_bounds__(256) void mlp_pass(
    const float* __restrict__ phi, const float* __restrict__ psi,
    const int* __restrict__ gi,
    const unsigned short* __restrict__ hin, const float* __restrict__ bnin,
    const float* __restrict__ W,
    unsigned short* __restrict__ hout, float* __restrict__ part,
    float* __restrict__ out)
{
  constexpr int OPT = COUT / 8;
  static_assert(OPT % 4 == 0, "OPT");
  __shared__ __align__(16) float Wt[CIN][COUT];
  __shared__ __align__(16) float ft[CIN][128];
  const int tid = threadIdx.x, blk = blockIdx.x;
  const size_t s0 = (size_t)blk * 128;

  for (int i = tid; i < CIN * COUT; i += 256){
    int o = i / CIN, c = i - o * CIN;
    Wt[c][o] = W[i];
  }

  if constexpr (MIN_ == 3){
    __shared__ int gidx[128];
    __shared__ float psm[4][64];
    const int b  = (int)(s0 >> 15);
    const int m0 = ((int)(s0 & 32767)) >> 5;
    if (tid < 128) gidx[tid] = gi[(size_t)b * 32768 + (size_t)m0 * K_ + tid];
    psm[tid >> 6][tid & 63] =
        psi[((size_t)b * M_ + m0 + (tid >> 6)) * 64 + (tid & 63)];
    __syncthreads();
    const int sl = tid >> 1, half = tid & 1;
    const int g = gidx[sl];
    const int mi = sl >> 5;
    const float* gp = phi + ((size_t)b * N_ + g) * 64 + half * 32;
    #pragma unroll
    for (int j = 0; j < 8; ++j){
      float4 v = *reinterpret_cast<const float4*>(gp + j * 4);
      int c = half * 32 + j * 4;
      ft[c][sl]     = fmaxf((v.x - psm[mi][c])     * bnin[c]     + bnin[CIN + c],     0.0f);
      ft[c + 1][sl] = fmaxf((v.y - psm[mi][c + 1]) * bnin[c + 1] + bnin[CIN + c + 1], 0.0f);
      ft[c + 2][sl] = fmaxf((v.z - psm[mi][c + 2]) * bnin[c + 2] + bnin[CIN + c + 2], 0.0f);
      ft[c + 3][sl] = fmaxf((v.w - psm[mi][c + 3]) * bnin[c + 3] + bnin[CIN + c + 3], 0.0f);
    }
  } else {
    const int sl = tid >> 1, c0 = (tid & 1) * 32;
    const unsigned short* hp = hin + (s0 + sl) * CIN + c0;
    #pragma unroll
    for (int j = 0; j < 4; ++j){
      ushort8 raw = *reinterpret_cast<const ushort8*>(hp + j * 8);
      #pragma unroll
      for (int e = 0; e < 8; ++e){
        int c = c0 + j * 8 + e;
        float h = bf2f(raw[e]);
        float f = h * bnin[c] + bnin[CIN + c];
        ft[c][sl] = fmaxf(f, 0.0f);
      }
    }
  }
  __syncthreads();

  const int sg = tid & 31, og = tid >> 5;
  float acc[4][OPT];
  #pragma unroll
  for (int i = 0; i < 4; ++i)
    #pragma unroll
    for (int o = 0; o < OPT; ++o) acc[i][o] = 0.0f;

  #pragma unroll 2
  for (int c = 0; c < CIN; ++c){
    float4 f = *reinterpret_cast<const float4*>(&ft[c][sg * 4]);
    float4 w[OPT / 4];
    #pragma unroll
    for (int j = 0; j < OPT / 4; ++j)
      w[j] = *reinterpret_cast<const float4*>(&Wt[c][og * OPT + j * 4]);
    const float fv[4] = {f.x, f.y, f.z, f.w};
    #pragma unroll
    for (int i = 0; i < 4; ++i){
      #pragma unroll
      for (int j = 0; j < OPT / 4; ++j){
        acc[i][j * 4 + 0] += fv[i] * w[j].x;
        acc[i][j * 4 + 1] += fv[i] * w[j].y;
        acc[i][j * 4 + 2] += fv[i] * w[j].z;
        acc[i][j * 4 + 3] += fv[i] * w[j].w;
      }
    }
  }

  if constexpr (MOUT_ == 0){
    #pragma unroll
    for (int i = 0; i < 4; ++i){
      size_t s = s0 + sg * 4 + i;
      unsigned pk[OPT / 2];
      #pragma unroll
      for (int o = 0; o < OPT / 2; ++o)
        pk[o] = f2bf(acc[i][2 * o]) | (f2bf(acc[i][2 * o + 1]) << 16);
      uint4* dst = reinterpret_cast<uint4*>(hout + s * COUT + og * OPT);
      dst[0] = make_uint4(pk[0], pk[1], pk[2], pk[3]);
      if constexpr (OPT == 16) dst[1] = make_uint4(pk[4], pk[5], pk[6], pk[7]);
    }
  }
  {
    float sv[OPT], sq[OPT];
    #pragma unroll
    for (int o = 0; o < OPT; ++o){
      float a0 = acc[0][o], a1 = acc[1][o], a2 = acc[2][o], a3 = acc[3][o];
      sv[o] = ((a0 + a1) + a2) + a3;
      sq[o] = ((a0 * a0 + a1 * a1) + a2 * a2) + a3 * a3;
    }
    #pragma unroll
    for (int off = 1; off < 32; off <<= 1){
      #pragma unroll
      for (int o = 0; o < OPT; ++o){
        sv[o] += __shfl_xor(sv[o], off);
        sq[o] += __shfl_xor(sq[o], off);
      }
    }
    if (sg == 0){
      #pragma unroll
      for (int o = 0; o < OPT; ++o){
        int ch = og * OPT + o;
        part[(size_t)(ch * 2) * 4096 + blk]     = sv[o];
        part[(size_t)(ch * 2 + 1) * 4096 + blk] = sq[o];
      }
    }
  }
  if constexpr (MOUT_ == 4){
    float amx[OPT], amn[OPT];
    #pragma unroll
    for (int o = 0; o < OPT; ++o){
      amx[o] = fmaxf(fmaxf(acc[0][o], acc[1][o]), fmaxf(acc[2][o], acc[3][o]));
      amn[o] = fminf(fminf(acc[0][o], acc[1][o]), fminf(acc[2][o], acc[3][o]));
    }
    #pragma unroll
    for (int off = 1; off < 8; off <<= 1){
      #pragma unroll
      for (int o = 0; o < OPT; ++o){
        amx[o] = fmaxf(amx[o], __shfl_xor(amx[o], off));
        amn[o] = fminf(amn[o], __shfl_xor(amn[o], off));
      }
    }
    if ((sg & 7) == 0){
      size_t mf = (s0 >> 5) + (sg >> 3);
      float* dmx = out + mf * COUT + og * OPT;
      float* dmn = dmx + MF_TOT;
      #pragma unroll
      for (int j = 0; j < OPT / 4; ++j){
        *reinterpret_cast<float4*>(dmx + j * 4) =
            make_float4(amx[j * 4], amx[j * 4 + 1], amx[j * 4 + 2], amx[j * 4 + 3]);
        *reinterpret_cast<float4*>(dmn + j * 4) =
            make_float4(amn[j * 4], amn[j * 4 + 1], amn[j * 4 + 2], amn[j * 4 + 3]);
      }
    }
  }
}

// ---------------- BN stats reduce + scale/shift -----------------------------
__global__ __launch_bounds__(256) void reduce_stats(const float* __restrict__ part,
                                                    const float* __restrict__ g,
                                                    const float* __restrict__ bb,
                                                    float* __restrict__ bn, int cout){
  const int ch = blockIdx.x, tid = threadIdx.x;
  float s = 0.f, q = 0.f;
  const float* ps = part + (size_t)(ch * 2) * 4096;
  const float* pq = part + (size_t)(ch * 2 + 1) * 4096;
  for (int i = tid; i < 4096; i += 256){ s += ps[i]; q += pq[i]; }
  #pragma unroll
  for (int off = 1; off < 64; off <<= 1){ s += __shfl_xor(s, off); q += __shfl_xor(q, off); }
  __shared__ float as_[4], aq_[4];
  if ((tid & 63) == 0){ as_[tid >> 6] = s; aq_[tid >> 6] = q; }
  __syncthreads();
  if (tid == 0){
    float S = as_[0] + as_[1] + as_[2] + as_[3];
    float Q = aq_[0] + aq_[1] + aq_[2] + aq_[3];
    const float cnt = 524288.0f;
    float mean = S / cnt;
    float var  = Q / cnt - mean * mean;
    float sc = g[ch] / sqrtf(var + 1e-5f);
    bn[ch] = sc;
    bn[cout + ch] = bb[ch] - mean * sc;
  }
}

// ---------------- finish: out = relu(max(a*mx+sh, a*mn+sh)) -----------------
__global__ __launch_bounds__(256) void bn_minmax_finish(const float* __restrict__ mxmn,
                                                        const float* __restrict__ bn2,
                                                        float* __restrict__ out){
  const int i = blockIdx.x * 256 + threadIdx.x;
  const int ch = i & 127;
  const float a = bn2[ch], sh = bn2[128 + ch];
  const float mx = mxmn[i], mn = mxmn[MF_TOT + i];
  out[i] = fmaxf(fmaxf(mx * a + sh, mn * a + sh), 0.0f);
}

extern "C" void kernel_launch(void* const* d_in, const int* in_sizes, int n_in,
                              void* d_out, int out_size, void* d_ws, size_t ws_size,
                              hipStream_t stream){
  (void)in_sizes; (void)n_in; (void)out_size; (void)ws_size;
  const float* xyz    = (const float*)d_in[0];
  const float* points = (const float*)d_in[1];
  const float* W0 = (const float*)d_in[2];
  const float* g0 = (const float*)d_in[3];
  const float* b0 = (const float*)d_in[4];
  const float* W1 = (const float*)d_in[5];
  const float* g1 = (const float*)d_in[6];
  const float* b1 = (const float*)d_in[7];
  const float* W2 = (const float*)d_in[8];
  const float* g2 = (const float*)d_in[9];
  const float* b2 = (const float*)d_in[10];

  float* out = (float*)d_out;
  float* o_newxyz = out;
  float* o_newpts = out + (size_t)B_ * M_ * 3;
  float* o_gind   = out + (size_t)B_ * M_ * 3 + (size_t)B_ * M_ * 128;

  char* ws = (char*)d_ws;
  int*   gi   = (int*)(ws + 0);                          // 2 MB
  float* part = (float*)(ws + (2ull << 20));             // 4 MB
  float* bn0  = (float*)(ws + (6ull << 20));
  float* bn1  = (float*)(ws + (6ull << 20) + 1024);
  float* bn2  = (float*)(ws + (6ull << 20) + 2048);
  float* phi  = (float*)(ws + (8ull << 20));             // 16 MB
  float* psi  = (float*)(ws + (24ull << 20));            // 4 MB
  unsigned short* h1 = (unsigned short*)(ws + (28ull << 20));   // 64 MB
  float* mxmn = (float*)(ws + (92ull << 20));            // 16 MB

  phi_kernel<<<512, 256, 0, stream>>>(xyz, points, W0, phi);
  fps_kernel<<<16, 512, 0, stream>>>(xyz, o_newxyz);
  ballq_psi_kernel<<<4160, 256, 0, stream>>>(xyz, o_newxyz, gi, o_gind, W0, psi);

  stats0_kernel<<<4096, 256, 0, stream>>>(phi, psi, gi, part);
  reduce_stats<<<64, 256, 0, stream>>>(part, g0, b0, bn0, 64);

  mlp_pass<64, 64, 3, 0><<<4096, 256, 0, stream>>>(phi, psi, gi,
      nullptr, bn0, W1, h1, part, nullptr);
  reduce_stats<<<64, 256, 0, stream>>>(part, g1, b1, bn1, 64);

  mlp_pass<64, 128, 1, 4><<<4096, 256, 0, stream>>>(nullptr, nullptr, nullptr,
      h1, bn1, W2, nullptr, part, mxmn);
  reduce_stats<<<128, 256, 0, stream>>>(part, g2, b2, bn2, 128);
  bn_minmax_finish<<<MF_TOT / 256, 256, 0, stream>>>(mxmn, bn2, o_newpts);
}

// Round 11
// 1047.624 us; speedup vs baseline: 1.0474x; 1.0474x over previous
//
#include <hip/hip_runtime.h>
#include <hip/hip_bf16.h>
#include <cstdint>

#define B_ 16
#define N_ 4096
#define CPTS_ 64
#define M_ 1024
#define K_ 32
#define MF_TOT 2097152   // B_*M_*128 pooled outputs

using ushort8 = __attribute__((ext_vector_type(8))) unsigned short;

static __device__ __forceinline__ unsigned f2bf(float x){
  unsigned u = __float_as_uint(x);
  return (u + 0x7fffu + ((u >> 16) & 1u)) >> 16;   // RTNE
}
static __device__ __forceinline__ float bf2f(unsigned short u){
  return __uint_as_float(((unsigned)u) << 16);
}

// DPP max step: v = max(v, dpp_shift(v)). Values are >= 0 so 0-fill is identity.
#define DPPMAX(v, ctrl)                                                        \
  do {                                                                         \
    int _t = __builtin_amdgcn_update_dpp(0, __float_as_int(v), (ctrl), 0xf,    \
                                         0xf, true);                           \
    (v) = fmaxf((v), __int_as_float(_t));                                      \
  } while (0)

// One distance update, all indices compile-time constant (named float4 comps).
#define STEP(MD, PX, PY, PZ, C, J)                                             \
  { float dx = PX.C - cx, dy = PY.C - cy, dz = PZ.C - cz;                      \
    float d = dx * dx; d = d + dy * dy; d = d + dz * dz;                       \
    float nm = fminf(MD.C, d); MD.C = nm;                                      \
    if (nm > bv){ bv = nm; bj = (J); } }
#define STEP4(MD, PX, PY, PZ, J0)                                              \
  STEP(MD, PX, PY, PZ, x, J0)                                                  \
  STEP(MD, PX, PY, PZ, y, (J0) + 1)                                            \
  STEP(MD, PX, PY, PZ, z, (J0) + 2)                                            \
  STEP(MD, PX, PY, PZ, w, (J0) + 3)

// ---------------- FPS: R7 exchange verbatim (670 us, proven floor) ----------
// R10's atomicMax exchange regressed (+57 us: dependent post-barrier read +
// serialized LDS atomics). 8-slot u64 write / parallel read / 7-op tree wins.
__global__ __launch_bounds__(512, 1) void fps_kernel(const float* __restrict__ xyz,
                                                     float* __restrict__ newxyz){
#pragma clang fp contract(off)
  __shared__ float xs[N_], ys[N_], zs[N_];
  __shared__ int inds_s[M_];
  __shared__ unsigned long long sv_[2][8];
  const int b = blockIdx.x, tid = threadIdx.x;
  const int lane = tid & 63, wv = tid >> 6;
  const float* xb = xyz + (size_t)b * N_ * 3;
  for (int i = tid; i < N_ * 3; i += 512){
    float v = xb[i];
    int n = i / 3, c = i - n * 3;
    if (c == 0) xs[n] = v; else if (c == 1) ys[n] = v; else zs[n] = v;
  }
  __syncthreads();
  // per-lane points: n = tid*8 + j  (wave w owns [w*512, w*512+512))
  const float4 px0 = *reinterpret_cast<const float4*>(&xs[tid * 8 + 0]);
  const float4 px1 = *reinterpret_cast<const float4*>(&xs[tid * 8 + 4]);
  const float4 py0 = *reinterpret_cast<const float4*>(&ys[tid * 8 + 0]);
  const float4 py1 = *reinterpret_cast<const float4*>(&ys[tid * 8 + 4]);
  const float4 pz0 = *reinterpret_cast<const float4*>(&zs[tid * 8 + 0]);
  const float4 pz1 = *reinterpret_cast<const float4*>(&zs[tid * 8 + 4]);
  float4 md0 = make_float4(1e10f, 1e10f, 1e10f, 1e10f);
  float4 md1 = md0;
  int far = 0;
  float cx = xs[0], cy = ys[0], cz = zs[0];
  for (int m = 0; m < M_; ++m){
    if (tid == 0) inds_s[m] = far;
    float bv = -1.0f; int bj = 0;
    STEP4(md0, px0, py0, pz0, 0)
    STEP4(md1, px1, py1, pz1, 4)
    // in-wave max via DPP (VALU, no LDS): result in lane 63
    float wm = bv;
    DPPMAX(wm, 0x111);  // row_shr:1
    DPPMAX(wm, 0x112);  // row_shr:2
    DPPMAX(wm, 0x114);  // row_shr:4
    DPPMAX(wm, 0x118);  // row_shr:8
    DPPMAX(wm, 0x142);  // row_bcast:15
    DPPMAX(wm, 0x143);  // row_bcast:31
    const float wmax = __int_as_float(
        __builtin_amdgcn_readlane(__float_as_int(wm), 63));
    // lowest tied lane = smallest n (lane ascending == n ascending per wave)
    unsigned long long tied = __ballot(bv == wmax);
    const int winlane = (int)__builtin_ctzll(tied);
    const int sl = m & 1;
    if (lane == winlane){
      int wn = tid * 8 + bj;
      sv_[sl][wv] = ((unsigned long long)__float_as_uint(wmax) << 32)
                  | (unsigned)(4095 - wn);     // (4095-n): smaller n wins on tie
    }
    __syncthreads();
    // 8-slot max tree; all pk distinct (distinct indices) => total order
    unsigned long long p0 = sv_[sl][0], p1 = sv_[sl][1], p2 = sv_[sl][2], p3 = sv_[sl][3];
    unsigned long long p4 = sv_[sl][4], p5 = sv_[sl][5], p6 = sv_[sl][6], p7 = sv_[sl][7];
    if (p1 > p0) p0 = p1;
    if (p3 > p2) p2 = p3;
    if (p5 > p4) p4 = p5;
    if (p7 > p6) p6 = p7;
    if (p2 > p0) p0 = p2;
    if (p6 > p4) p4 = p6;
    if (p4 > p0) p0 = p4;
    far = 4095 - (int)(p0 & 0xffffffffu);
    cx = xs[far]; cy = ys[far]; cz = zs[far];   // broadcast LDS reads
  }
  __syncthreads();
  for (int t = tid; t < M_; t += 512){
    int id = inds_s[t];
    size_t o = ((size_t)b * M_ + t) * 3;
    newxyz[o] = xs[id]; newxyz[o + 1] = ys[id]; newxyz[o + 2] = zs[id];
  }
}

// ---------------- phi: per-point layer-0 matmul (no gather) -----------------
// phi0[p] = W0 . [xyz[p]; points[p]]  (512 blocks x 128 points)
__global__ __launch_bounds__(256) void phi_kernel(const float* __restrict__ xyz,
                                                  const float* __restrict__ points,
                                                  const float* __restrict__ W,
                                                  float* __restrict__ phi){
  __shared__ __align__(16) float Wt[67][64];
  __shared__ __align__(16) float ft[67][128];
  const int tid = threadIdx.x, blk = blockIdx.x;
  const int p0 = blk * 128;                 // global point id (batch-contiguous)
  for (int i = tid; i < 67 * 64; i += 256){
    int o = i / 67, c = i - o * 67;
    Wt[c][o] = W[i];
  }
  const int sl = tid >> 1, half = tid & 1;
  const int p = p0 + sl;
  const float* ps = points + (size_t)p * CPTS_ + half * 32;
  #pragma unroll
  for (int j = 0; j < 8; ++j){
    float4 v = *reinterpret_cast<const float4*>(ps + j * 4);
    int c = 3 + half * 32 + j * 4;
    ft[c][sl] = v.x; ft[c + 1][sl] = v.y; ft[c + 2][sl] = v.z; ft[c + 3][sl] = v.w;
  }
  if (half == 0){
    const float* xp = xyz + (size_t)p * 3;
    ft[0][sl] = xp[0]; ft[1][sl] = xp[1]; ft[2][sl] = xp[2];   // raw xyz, no centering
  }
  __syncthreads();
  const int sg = tid & 31, og = tid >> 5;
  float acc[4][8];
  #pragma unroll
  for (int i = 0; i < 4; ++i)
    #pragma unroll
    for (int o = 0; o < 8; ++o) acc[i][o] = 0.0f;
  #pragma unroll 2
  for (int c = 0; c < 67; ++c){
    float4 f = *reinterpret_cast<const float4*>(&ft[c][sg * 4]);
    float4 w0 = *reinterpret_cast<const float4*>(&Wt[c][og * 8]);
    float4 w1 = *reinterpret_cast<const float4*>(&Wt[c][og * 8 + 4]);
    const float fv[4] = {f.x, f.y, f.z, f.w};
    #pragma unroll
    for (int i = 0; i < 4; ++i){
      acc[i][0] += fv[i] * w0.x; acc[i][1] += fv[i] * w0.y;
      acc[i][2] += fv[i] * w0.z; acc[i][3] += fv[i] * w0.w;
      acc[i][4] += fv[i] * w1.x; acc[i][5] += fv[i] * w1.y;
      acc[i][6] += fv[i] * w1.z; acc[i][7] += fv[i] * w1.w;
    }
  }
  #pragma unroll
  for (int i = 0; i < 4; ++i){
    float* dst = phi + (size_t)(p0 + sg * 4 + i) * 64 + og * 8;
    *reinterpret_cast<float4*>(dst)     = make_float4(acc[i][0], acc[i][1], acc[i][2], acc[i][3]);
    *reinterpret_cast<float4*>(dst + 4) = make_float4(acc[i][4], acc[i][5], acc[i][6], acc[i][7]);
  }
}

// ---------------- Ball query (blocks 0..4095) + psi (blocks 4096..4159) -----
// psi0[m] = W0a . new_xyz[m]  (first 3 input channels of W0)
__global__ __launch_bounds__(256) void ballq_psi_kernel(const float* __restrict__ xyz,
                                                        const float* __restrict__ newxyz,
                                                        int* __restrict__ gi,
                                                        float* __restrict__ gif,
                                                        const float* __restrict__ W0,
                                                        float* __restrict__ psi){
  if (blockIdx.x >= 4096){
    const int mi = (blockIdx.x - 4096) * 256 + threadIdx.x;   // 0..16383
    const float x = newxyz[(size_t)mi * 3];
    const float y = newxyz[(size_t)mi * 3 + 1];
    const float z = newxyz[(size_t)mi * 3 + 2];
    float* dst = psi + (size_t)mi * 64;
    #pragma unroll
    for (int o4 = 0; o4 < 16; ++o4){
      float v[4];
      #pragma unroll
      for (int e = 0; e < 4; ++e){
        int o = o4 * 4 + e;
        v[e] = fmaf(z, W0[o * 67 + 2], fmaf(y, W0[o * 67 + 1], x * W0[o * 67]));
      }
      *reinterpret_cast<float4*>(dst + o4 * 4) = make_float4(v[0], v[1], v[2], v[3]);
    }
    return;
  }
  const int gw = (blockIdx.x * 256 + threadIdx.x) >> 6;
  const int lane = threadIdx.x & 63;
  const int b = gw >> 10, m = gw & 1023;
  const float* xb = xyz + (size_t)b * N_ * 3;
  const size_t no = (size_t)b * M_ + m;
  const float cx = newxyz[no * 3], cy = newxyz[no * 3 + 1], cz = newxyz[no * 3 + 2];
  const float sm = fmaf(cz, cz, fmaf(cy, cy, cx * cx));
  int total = 0, first_idx = 0; bool havef = false;
  int*   gd = gi  + no * K_;
  float* fd = gif + no * K_;
  for (int ch = 0; ch < 64 && total < K_; ++ch){
    const int n = ch * 64 + lane;
    const float x = xb[n * 3], y = xb[n * 3 + 1], z = xb[n * 3 + 2];
    const float sn = fmaf(z, z, fmaf(y, y, x * x));
    const float dt = fmaf(z, cz, fmaf(y, cy, x * cx));
    float d2 = (sm + sn) - 2.0f * dt;                 // ref: |a|^2+|b|^2-2ab
    float dist = sqrtf(fmaxf(d2, 0.0f));
    bool pred = !(dist > 0.2f);
    unsigned long long mask = __ballot(pred);
    if (!havef && mask){ havef = true; first_idx = ch * 64 + (int)__builtin_ctzll(mask); }
    if (pred){
      int rank = total + (int)__popcll(mask & ((1ull << lane) - 1ull));
      if (rank < K_){ gd[rank] = n; fd[rank] = (float)n; }
    }
    total += (int)__popcll(mask);
  }
  if (total < K_ && lane >= total && lane < K_){ gd[lane] = first_idx; fd[lane] = (float)first_idx; }
}

// ---------------- stats0: BN0 sums over gathered (phi - psi) ----------------
__global__ __launch_bounds__(256) void stats0_kernel(const float* __restrict__ phi,
                                                     const float* __restrict__ psi,
                                                     const int* __restrict__ gi,
                                                     float* __restrict__ part){
  __shared__ int gidx[128];
  __shared__ float psm[4][64];
  const int tid = threadIdx.x, blk = blockIdx.x;
  const size_t s0 = (size_t)blk * 128;
  const int b  = (int)(s0 >> 15);
  const int m0 = ((int)(s0 & 32767)) >> 5;
  if (tid < 128) gidx[tid] = gi[(size_t)b * 32768 + (size_t)m0 * K_ + tid];
  psm[tid >> 6][tid & 63] =
      psi[((size_t)b * M_ + m0 + (tid >> 6)) * 64 + (tid & 63)];
  __syncthreads();
  const int sg = tid & 31, og = tid >> 5;
  const int mi = sg >> 3;
  float sv[8], sq[8];
  #pragma unroll
  for (int o = 0; o < 8; ++o){ sv[o] = 0.f; sq[o] = 0.f; }
  #pragma unroll
  for (int i = 0; i < 4; ++i){
    const int g = gidx[sg * 4 + i];
    const float* gp = phi + ((size_t)b * N_ + g) * 64 + og * 8;
    float4 a0 = *reinterpret_cast<const float4*>(gp);
    float4 a1 = *reinterpret_cast<const float4*>(gp + 4);
    const float pv[8] = {a0.x, a0.y, a0.z, a0.w, a1.x, a1.y, a1.z, a1.w};
    #pragma unroll
    for (int o = 0; o < 8; ++o){
      float v = pv[o] - psm[mi][og * 8 + o];
      sv[o] += v; sq[o] += v * v;
    }
  }
  #pragma unroll
  for (int off = 1; off < 32; off <<= 1){
    #pragma unroll
    for (int o = 0; o < 8; ++o){
      sv[o] += __shfl_xor(sv[o], off);
      sq[o] += __shfl_xor(sq[o], off);
    }
  }
  if (sg == 0){
    #pragma unroll
    for (int o = 0; o < 8; ++o){
      int ch = og * 8 + o;
      part[(size_t)(ch * 2) * 4096 + blk]     = sv[o];
      part[(size_t)(ch * 2 + 1) * 4096 + blk] = sq[o];
    }
  }
}

// ---------------- MLP pass ---------------------------------------------------
// MIN_: 1 = read h_in (bf16) + BN + ReLU;  3 = gather (phi - psi) + BN0 + ReLU
// MOUT_: 0 = store h (bf16) + partial stats
//        4 = partial stats + raw-h max/min over K (f32) -> out (mx | mn)
template<int CIN, int COUT, int MIN_, int MOUT_>
__global__ __launch_bounds__(256) void mlp_pass(
    const float* __restrict__ phi, const float* __restrict__ psi,
    const int* __restrict__ gi,
    const unsigned short* __restrict__ hin, const float* __restrict__ bnin,
    const float* __restrict__ W,
    unsigned short* __restrict__ hout, float* __restrict__ part,
    float* __restrict__ out)
{
  constexpr int OPT = COUT / 8;
  static_assert(OPT % 4 == 0, "OPT");
  __shared__ __align__(16) float Wt[CIN][COUT];
  __shared__ __align__(16) float ft[CIN][128];
  const int tid = threadIdx.x, blk = blockIdx.x;
  const size_t s0 = (size_t)blk * 128;

  for (int i = tid; i < CIN * COUT; i += 256){
    int o = i / CIN, c = i - o * CIN;
    Wt[c][o] = W[i];
  }

  if constexpr (MIN_ == 3){
    __shared__ int gidx[128];
    __shared__ float psm[4][64];
    const int b  = (int)(s0 >> 15);
    const int m0 = ((int)(s0 & 32767)) >> 5;
    if (tid < 128) gidx[tid] = gi[(size_t)b * 32768 + (size_t)m0 * K_ + tid];
    psm[tid >> 6][tid & 63] =
        psi[((size_t)b * M_ + m0 + (tid >> 6)) * 64 + (tid & 63)];
    __syncthreads();
    const int sl = tid >> 1, half = tid & 1;
    const int g = gidx[sl];
    const int mi = sl >> 5;
    const float* gp = phi + ((size_t)b * N_ + g) * 64 + half * 32;
    #pragma unroll
    for (int j = 0; j < 8; ++j){
      float4 v = *reinterpret_cast<const float4*>(gp + j * 4);
      int c = half * 32 + j * 4;
      ft[c][sl]     = fmaxf((v.x - psm[mi][c])     * bnin[c]     + bnin[CIN + c],     0.0f);
      ft[c + 1][sl] = fmaxf((v.y - psm[mi][c + 1]) * bnin[c + 1] + bnin[CIN + c + 1], 0.0f);
      ft[c + 2][sl] = fmaxf((v.z - psm[mi][c + 2]) * bnin[c + 2] + bnin[CIN + c + 2], 0.0f);
      ft[c + 3][sl] = fmaxf((v.w - psm[mi][c + 3]) * bnin[c + 3] + bnin[CIN + c + 3], 0.0f);
    }
  } else {
    const int sl = tid >> 1, c0 = (tid & 1) * 32;
    const unsigned short* hp = hin + (s0 + sl) * CIN + c0;
    #pragma unroll
    for (int j = 0; j < 4; ++j){
      ushort8 raw = *reinterpret_cast<const ushort8*>(hp + j * 8);
      #pragma unroll
      for (int e = 0; e < 8; ++e){
        int c = c0 + j * 8 + e;
        float h = bf2f(raw[e]);
        float f = h * bnin[c] + bnin[CIN + c];
        ft[c][sl] = fmaxf(f, 0.0f);
      }
    }
  }
  __syncthreads();

  const int sg = tid & 31, og = tid >> 5;
  float acc[4][OPT];
  #pragma unroll
  for (int i = 0; i < 4; ++i)
    #pragma unroll
    for (int o = 0; o < OPT; ++o) acc[i][o] = 0.0f;

  #pragma unroll 2
  for (int c = 0; c < CIN; ++c){
    float4 f = *reinterpret_cast<const float4*>(&ft[c][sg * 4]);
    float4 w[OPT / 4];
    #pragma unroll
    for (int j = 0; j < OPT / 4; ++j)
      w[j] = *reinterpret_cast<const float4*>(&Wt[c][og * OPT + j * 4]);
    const float fv[4] = {f.x, f.y, f.z, f.w};
    #pragma unroll
    for (int i = 0; i < 4; ++i){
      #pragma unroll
      for (int j = 0; j < OPT / 4; ++j){
        acc[i][j * 4 + 0] += fv[i] * w[j].x;
        acc[i][j * 4 + 1] += fv[i] * w[j].y;
        acc[i][j * 4 + 2] += fv[i] * w[j].z;
        acc[i][j * 4 + 3] += fv[i] * w[j].w;
      }
    }
  }

  if constexpr (MOUT_ == 0){
    #pragma unroll
    for (int i = 0; i < 4; ++i){
      size_t s = s0 + sg * 4 + i;
      unsigned pk[OPT / 2];
      #pragma unroll
      for (int o = 0; o < OPT / 2; ++o)
        pk[o] = f2bf(acc[i][2 * o]) | (f2bf(acc[i][2 * o + 1]) << 16);
      uint4* dst = reinterpret_cast<uint4*>(hout + s * COUT + og * OPT);
      dst[0] = make_uint4(pk[0], pk[1], pk[2], pk[3]);
      if constexpr (OPT == 16) dst[1] = make_uint4(pk[4], pk[5], pk[6], pk[7]);
    }
  }
  {
    float sv[OPT], sq[OPT];
    #pragma unroll
    for (int o = 0; o < OPT; ++o){
      float a0 = acc[0][o], a1 = acc[1][o], a2 = acc[2][o], a3 = acc[3][o];
      sv[o] = ((a0 + a1) + a2) + a3;
      sq[o] = ((a0 * a0 + a1 * a1) + a2 * a2) + a3 * a3;
    }
    #pragma unroll
    for (int off = 1; off < 32; off <<= 1){
      #pragma unroll
      for (int o = 0; o < OPT; ++o){
        sv[o] += __shfl_xor(sv[o], off);
        sq[o] += __shfl_xor(sq[o], off);
      }
    }
    if (sg == 0){
      #pragma unroll
      for (int o = 0; o < OPT; ++o){
        int ch = og * OPT + o;
        part[(size_t)(ch * 2) * 4096 + blk]     = sv[o];
        part[(size_t)(ch * 2 + 1) * 4096 + blk] = sq[o];
      }
    }
  }
  if constexpr (MOUT_ == 4){
    float amx[OPT], amn[OPT];
    #pragma unroll
    for (int o = 0; o < OPT; ++o){
      amx[o] = fmaxf(fmaxf(acc[0][o], acc[1][o]), fmaxf(acc[2][o], acc[3][o]));
      amn[o] = fminf(fminf(acc[0][o], acc[1][o]), fminf(acc[2][o], acc[3][o]));
    }
    #pragma unroll
    for (int off = 1; off < 8; off <<= 1){
      #pragma unroll
      for (int o = 0; o < OPT; ++o){
        amx[o] = fmaxf(amx[o], __shfl_xor(amx[o], off));
        amn[o] = fminf(amn[o], __shfl_xor(amn[o], off));
      }
    }
    if ((sg & 7) == 0){
      size_t mf = (s0 >> 5) + (sg >> 3);
      float* dmx = out + mf * COUT + og * OPT;
      float* dmn = dmx + MF_TOT;
      #pragma unroll
      for (int j = 0; j < OPT / 4; ++j){
        *reinterpret_cast<float4*>(dmx + j * 4) =
            make_float4(amx[j * 4], amx[j * 4 + 1], amx[j * 4 + 2], amx[j * 4 + 3]);
        *reinterpret_cast<float4*>(dmn + j * 4) =
            make_float4(amn[j * 4], amn[j * 4 + 1], amn[j * 4 + 2], amn[j * 4 + 3]);
      }
    }
  }
}

// ---------------- BN stats reduce + scale/shift -----------------------------
__global__ __launch_bounds__(256) void reduce_stats(const float* __restrict__ part,
                                                    const float* __restrict__ g,
                                                    const float* __restrict__ bb,
                                                    float* __restrict__ bn, int cout){
  const int ch = blockIdx.x, tid = threadIdx.x;
  float s = 0.f, q = 0.f;
  const float* ps = part + (size_t)(ch * 2) * 4096;
  const float* pq = part + (size_t)(ch * 2 + 1) * 4096;
  for (int i = tid; i < 4096; i += 256){ s += ps[i]; q += pq[i]; }
  #pragma unroll
  for (int off = 1; off < 64; off <<= 1){ s += __shfl_xor(s, off); q += __shfl_xor(q, off); }
  __shared__ float as_[4], aq_[4];
  if ((tid & 63) == 0){ as_[tid >> 6] = s; aq_[tid >> 6] = q; }
  __syncthreads();
  if (tid == 0){
    float S = as_[0] + as_[1] + as_[2] + as_[3];
    float Q = aq_[0] + aq_[1] + aq_[2] + aq_[3];
    const float cnt = 524288.0f;
    float mean = S / cnt;
    float var  = Q / cnt - mean * mean;
    float sc = g[ch] / sqrtf(var + 1e-5f);
    bn[ch] = sc;
    bn[cout + ch] = bb[ch] - mean * sc;
  }
}

// ---------------- finish: out = relu(max(a*mx+sh, a*mn+sh)) -----------------
__global__ __launch_bounds__(256) void bn_minmax_finish(const float* __restrict__ mxmn,
                                                        const float* __restrict__ bn2,
                                                        float* __restrict__ out){
  const int i = blockIdx.x * 256 + threadIdx.x;
  const int ch = i & 127;
  const float a = bn2[ch], sh = bn2[128 + ch];
  const float mx = mxmn[i], mn = mxmn[MF_TOT + i];
  out[i] = fmaxf(fmaxf(mx * a + sh, mn * a + sh), 0.0f);
}

extern "C" void kernel_launch(void* const* d_in, const int* in_sizes, int n_in,
                              void* d_out, int out_size, void* d_ws, size_t ws_size,
                              hipStream_t stream){
  (void)in_sizes; (void)n_in; (void)out_size; (void)ws_size;
  const float* xyz    = (const float*)d_in[0];
  const float* points = (const float*)d_in[1];
  const float* W0 = (const float*)d_in[2];
  const float* g0 = (const float*)d_in[3];
  const float* b0 = (const float*)d_in[4];
  const float* W1 = (const float*)d_in[5];
  const float* g1 = (const float*)d_in[6];
  const float* b1 = (const float*)d_in[7];
  const float* W2 = (const float*)d_in[8];
  const float* g2 = (const float*)d_in[9];
  const float* b2 = (const float*)d_in[10];

  float* out = (float*)d_out;
  float* o_newxyz = out;
  float* o_newpts = out + (size_t)B_ * M_ * 3;
  float* o_gind   = out + (size_t)B_ * M_ * 3 + (size_t)B_ * M_ * 128;

  char* ws = (char*)d_ws;
  int*   gi   = (int*)(ws + 0);                          // 2 MB
  float* part = (float*)(ws + (2ull << 20));             // 4 MB
  float* bn0  = (float*)(ws + (6ull << 20));
  float* bn1  = (float*)(ws + (6ull << 20) + 1024);
  float* bn2  = (float*)(ws + (6ull << 20) + 2048);
  float* phi  = (float*)(ws + (8ull << 20));             // 16 MB
  float* psi  = (float*)(ws + (24ull << 20));            // 4 MB
  unsigned short* h1 = (unsigned short*)(ws + (28ull << 20));   // 64 MB
  float* mxmn = (float*)(ws + (92ull << 20));            // 16 MB

  phi_kernel<<<512, 256, 0, stream>>>(xyz, points, W0, phi);
  fps_kernel<<<16, 512, 0, stream>>>(xyz, o_newxyz);
  ballq_psi_kernel<<<4160, 256, 0, stream>>>(xyz, o_newxyz, gi, o_gind, W0, psi);

  stats0_kernel<<<4096, 256, 0, stream>>>(phi, psi, gi, part);
  reduce_stats<<<64, 256, 0, stream>>>(part, g0, b0, bn0, 64);

  mlp_pass<64, 64, 3, 0><<<4096, 256, 0, stream>>>(phi, psi, gi,
      nullptr, bn0, W1, h1, part, nullptr);
  reduce_stats<<<64, 256, 0, stream>>>(part, g1, b1, bn1, 64);

  mlp_pass<64, 128, 1, 4><<<4096, 256, 0, stream>>>(nullptr, nullptr, nullptr,
      h1, bn1, W2, nullptr, part, mxmn);
  reduce_stats<<<128, 256, 0, stream>>>(part, g2, b2, bn2, 128);
  bn_minmax_finish<<<MF_TOT / 256, 256, 0, stream>>>(mxmn, bn2, o_newpts);
}

// Round 12
// 937.956 us; speedup vs baseline: 1.1698x; 1.1169x over previous
//
#include <hip/hip_runtime.h>
#include <hip/hip_bf16.h>
#include <cstdint>

#define B_ 16
#define N_ 4096
#define CPTS_ 64
#define M_ 1024
#define K_ 32
#define MF_TOT 2097152   // B_*M_*128 pooled outputs

using ushort8 = __attribute__((ext_vector_type(8))) unsigned short;
using bf16x8  = __attribute__((ext_vector_type(8))) short;
using f32x4v  = __attribute__((ext_vector_type(4))) float;

static __device__ __forceinline__ unsigned f2bf(float x){
  unsigned u = __float_as_uint(x);
  return (u + 0x7fffu + ((u >> 16) & 1u)) >> 16;   // RTNE
}
static __device__ __forceinline__ float bf2f(unsigned short u){
  return __uint_as_float(((unsigned)u) << 16);
}

// DPP max step: v = max(v, dpp_shift(v)). Values are >= 0 so 0-fill is identity.
#define DPPMAX(v, ctrl)                                                        \
  do {                                                                         \
    int _t = __builtin_amdgcn_update_dpp(0, __float_as_int(v), (ctrl), 0xf,    \
                                         0xf, true);                           \
    (v) = fmaxf((v), __int_as_float(_t));                                      \
  } while (0)

// One distance update, all indices compile-time constant (named float4 comps).
#define STEP(MD, PX, PY, PZ, C, J)                                             \
  { float dx = PX.C - cx, dy = PY.C - cy, dz = PZ.C - cz;                      \
    float d = dx * dx; d = d + dy * dy; d = d + dz * dz;                       \
    float nm = fminf(MD.C, d); MD.C = nm;                                      \
    if (nm > bv){ bv = nm; bj = (J); } }
#define STEP4(MD, PX, PY, PZ, J0)                                              \
  STEP(MD, PX, PY, PZ, x, J0)                                                  \
  STEP(MD, PX, PY, PZ, y, (J0) + 1)                                            \
  STEP(MD, PX, PY, PZ, z, (J0) + 2)                                            \
  STEP(MD, PX, PY, PZ, w, (J0) + 3)

// ---------------- FPS: R7 exchange verbatim (670 us, proven floor) ----------
__global__ __launch_bounds__(512, 1) void fps_kernel(const float* __restrict__ xyz,
                                                     float* __restrict__ newxyz){
#pragma clang fp contract(off)
  __shared__ float xs[N_], ys[N_], zs[N_];
  __shared__ int inds_s[M_];
  __shared__ unsigned long long sv_[2][8];
  const int b = blockIdx.x, tid = threadIdx.x;
  const int lane = tid & 63, wv = tid >> 6;
  const float* xb = xyz + (size_t)b * N_ * 3;
  for (int i = tid; i < N_ * 3; i += 512){
    float v = xb[i];
    int n = i / 3, c = i - n * 3;
    if (c == 0) xs[n] = v; else if (c == 1) ys[n] = v; else zs[n] = v;
  }
  __syncthreads();
  const float4 px0 = *reinterpret_cast<const float4*>(&xs[tid * 8 + 0]);
  const float4 px1 = *reinterpret_cast<const float4*>(&xs[tid * 8 + 4]);
  const float4 py0 = *reinterpret_cast<const float4*>(&ys[tid * 8 + 0]);
  const float4 py1 = *reinterpret_cast<const float4*>(&ys[tid * 8 + 4]);
  const float4 pz0 = *reinterpret_cast<const float4*>(&zs[tid * 8 + 0]);
  const float4 pz1 = *reinterpret_cast<const float4*>(&zs[tid * 8 + 4]);
  float4 md0 = make_float4(1e10f, 1e10f, 1e10f, 1e10f);
  float4 md1 = md0;
  int far = 0;
  float cx = xs[0], cy = ys[0], cz = zs[0];
  for (int m = 0; m < M_; ++m){
    if (tid == 0) inds_s[m] = far;
    float bv = -1.0f; int bj = 0;
    STEP4(md0, px0, py0, pz0, 0)
    STEP4(md1, px1, py1, pz1, 4)
    float wm = bv;
    DPPMAX(wm, 0x111);  // row_shr:1
    DPPMAX(wm, 0x112);  // row_shr:2
    DPPMAX(wm, 0x114);  // row_shr:4
    DPPMAX(wm, 0x118);  // row_shr:8
    DPPMAX(wm, 0x142);  // row_bcast:15
    DPPMAX(wm, 0x143);  // row_bcast:31
    const float wmax = __int_as_float(
        __builtin_amdgcn_readlane(__float_as_int(wm), 63));
    unsigned long long tied = __ballot(bv == wmax);
    const int winlane = (int)__builtin_ctzll(tied);
    const int sl = m & 1;
    if (lane == winlane){
      int wn = tid * 8 + bj;
      sv_[sl][wv] = ((unsigned long long)__float_as_uint(wmax) << 32)
                  | (unsigned)(4095 - wn);     // (4095-n): smaller n wins on tie
    }
    __syncthreads();
    unsigned long long p0 = sv_[sl][0], p1 = sv_[sl][1], p2 = sv_[sl][2], p3 = sv_[sl][3];
    unsigned long long p4 = sv_[sl][4], p5 = sv_[sl][5], p6 = sv_[sl][6], p7 = sv_[sl][7];
    if (p1 > p0) p0 = p1;
    if (p3 > p2) p2 = p3;
    if (p5 > p4) p4 = p5;
    if (p7 > p6) p6 = p7;
    if (p2 > p0) p0 = p2;
    if (p6 > p4) p4 = p6;
    if (p4 > p0) p0 = p4;
    far = 4095 - (int)(p0 & 0xffffffffu);
    cx = xs[far]; cy = ys[far]; cz = zs[far];   // broadcast LDS reads
  }
  __syncthreads();
  for (int t = tid; t < M_; t += 512){
    int id = inds_s[t];
    size_t o = ((size_t)b * M_ + t) * 3;
    newxyz[o] = xs[id]; newxyz[o + 1] = ys[id]; newxyz[o + 2] = zs[id];
  }
}

// ---------------- phi: per-point layer-0 matmul (no gather) -----------------
__global__ __launch_bounds__(256) void phi_kernel(const float* __restrict__ xyz,
                                                  const float* __restrict__ points,
                                                  const float* __restrict__ W,
                                                  float* __restrict__ phi){
  __shared__ __align__(16) float Wt[67][64];
  __shared__ __align__(16) float ft[67][128];
  const int tid = threadIdx.x, blk = blockIdx.x;
  const int p0 = blk * 128;
  for (int i = tid; i < 67 * 64; i += 256){
    int o = i / 67, c = i - o * 67;
    Wt[c][o] = W[i];
  }
  const int sl = tid >> 1, half = tid & 1;
  const int p = p0 + sl;
  const float* ps = points + (size_t)p * CPTS_ + half * 32;
  #pragma unroll
  for (int j = 0; j < 8; ++j){
    float4 v = *reinterpret_cast<const float4*>(ps + j * 4);
    int c = 3 + half * 32 + j * 4;
    ft[c][sl] = v.x; ft[c + 1][sl] = v.y; ft[c + 2][sl] = v.z; ft[c + 3][sl] = v.w;
  }
  if (half == 0){
    const float* xp = xyz + (size_t)p * 3;
    ft[0][sl] = xp[0]; ft[1][sl] = xp[1]; ft[2][sl] = xp[2];
  }
  __syncthreads();
  const int sg = tid & 31, og = tid >> 5;
  float acc[4][8];
  #pragma unroll
  for (int i = 0; i < 4; ++i)
    #pragma unroll
    for (int o = 0; o < 8; ++o) acc[i][o] = 0.0f;
  #pragma unroll 2
  for (int c = 0; c < 67; ++c){
    float4 f = *reinterpret_cast<const float4*>(&ft[c][sg * 4]);
    float4 w0 = *reinterpret_cast<const float4*>(&Wt[c][og * 8]);
    float4 w1 = *reinterpret_cast<const float4*>(&Wt[c][og * 8 + 4]);
    const float fv[4] = {f.x, f.y, f.z, f.w};
    #pragma unroll
    for (int i = 0; i < 4; ++i){
      acc[i][0] += fv[i] * w0.x; acc[i][1] += fv[i] * w0.y;
      acc[i][2] += fv[i] * w0.z; acc[i][3] += fv[i] * w0.w;
      acc[i][4] += fv[i] * w1.x; acc[i][5] += fv[i] * w1.y;
      acc[i][6] += fv[i] * w1.z; acc[i][7] += fv[i] * w1.w;
    }
  }
  #pragma unroll
  for (int i = 0; i < 4; ++i){
    float* dst = phi + (size_t)(p0 + sg * 4 + i) * 64 + og * 8;
    *reinterpret_cast<float4*>(dst)     = make_float4(acc[i][0], acc[i][1], acc[i][2], acc[i][3]);
    *reinterpret_cast<float4*>(dst + 4) = make_float4(acc[i][4], acc[i][5], acc[i][6], acc[i][7]);
  }
}

// ---------------- Ball query (blocks 0..4095) + psi (blocks 4096..4159) -----
__global__ __launch_bounds__(256) void ballq_psi_kernel(const float* __restrict__ xyz,
                                                        const float* __restrict__ newxyz,
                                                        int* __restrict__ gi,
                                                        float* __restrict__ gif,
                                                        const float* __restrict__ W0,
                                                        float* __restrict__ psi){
  if (blockIdx.x >= 4096){
    const int mi = (blockIdx.x - 4096) * 256 + threadIdx.x;
    const float x = newxyz[(size_t)mi * 3];
    const float y = newxyz[(size_t)mi * 3 + 1];
    const float z = newxyz[(size_t)mi * 3 + 2];
    float* dst = psi + (size_t)mi * 64;
    #pragma unroll
    for (int o4 = 0; o4 < 16; ++o4){
      float v[4];
      #pragma unroll
      for (int e = 0; e < 4; ++e){
        int o = o4 * 4 + e;
        v[e] = fmaf(z, W0[o * 67 + 2], fmaf(y, W0[o * 67 + 1], x * W0[o * 67]));
      }
      *reinterpret_cast<float4*>(dst + o4 * 4) = make_float4(v[0], v[1], v[2], v[3]);
    }
    return;
  }
  const int gw = (blockIdx.x * 256 + threadIdx.x) >> 6;
  const int lane = threadIdx.x & 63;
  const int b = gw >> 10, m = gw & 1023;
  const float* xb = xyz + (size_t)b * N_ * 3;
  const size_t no = (size_t)b * M_ + m;
  const float cx = newxyz[no * 3], cy = newxyz[no * 3 + 1], cz = newxyz[no * 3 + 2];
  const float sm = fmaf(cz, cz, fmaf(cy, cy, cx * cx));
  int total = 0, first_idx = 0; bool havef = false;
  int*   gd = gi  + no * K_;
  float* fd = gif + no * K_;
  for (int ch = 0; ch < 64 && total < K_; ++ch){
    const int n = ch * 64 + lane;
    const float x = xb[n * 3], y = xb[n * 3 + 1], z = xb[n * 3 + 2];
    const float sn = fmaf(z, z, fmaf(y, y, x * x));
    const float dt = fmaf(z, cz, fmaf(y, cy, x * cx));
    float d2 = (sm + sn) - 2.0f * dt;                 // ref: |a|^2+|b|^2-2ab
    float dist = sqrtf(fmaxf(d2, 0.0f));
    bool pred = !(dist > 0.2f);
    unsigned long long mask = __ballot(pred);
    if (!havef && mask){ havef = true; first_idx = ch * 64 + (int)__builtin_ctzll(mask); }
    if (pred){
      int rank = total + (int)__popcll(mask & ((1ull << lane) - 1ull));
      if (rank < K_){ gd[rank] = n; fd[rank] = (float)n; }
    }
    total += (int)__popcll(mask);
  }
  if (total < K_ && lane >= total && lane < K_){ gd[lane] = first_idx; fd[lane] = (float)first_idx; }
}

// ---------------- stats0: BN0 sums over gathered (phi - psi) ----------------
__global__ __launch_bounds__(256) void stats0_kernel(const float* __restrict__ phi,
                                                     const float* __restrict__ psi,
                                                     const int* __restrict__ gi,
                                                     float* __restrict__ part){
  __shared__ int gidx[128];
  __shared__ float psm[4][64];
  const int tid = threadIdx.x, blk = blockIdx.x;
  const size_t s0 = (size_t)blk * 128;
  const int b  = (int)(s0 >> 15);
  const int m0 = ((int)(s0 & 32767)) >> 5;
  if (tid < 128) gidx[tid] = gi[(size_t)b * 32768 + (size_t)m0 * K_ + tid];
  psm[tid >> 6][tid & 63] =
      psi[((size_t)b * M_ + m0 + (tid >> 6)) * 64 + (tid & 63)];
  __syncthreads();
  const int sg = tid & 31, og = tid >> 5;
  const int mi = sg >> 3;
  float sv[8], sq[8];
  #pragma unroll
  for (int o = 0; o < 8; ++o){ sv[o] = 0.f; sq[o] = 0.f; }
  #pragma unroll
  for (int i = 0; i < 4; ++i){
    const int g = gidx[sg * 4 + i];
    const float* gp = phi + ((size_t)b * N_ + g) * 64 + og * 8;
    float4 a0 = *reinterpret_cast<const float4*>(gp);
    float4 a1 = *reinterpret_cast<const float4*>(gp + 4);
    const float pv[8] = {a0.x, a0.y, a0.z, a0.w, a1.x, a1.y, a1.z, a1.w};
    #pragma unroll
    for (int o = 0; o < 8; ++o){
      float v = pv[o] - psm[mi][og * 8 + o];
      sv[o] += v; sq[o] += v * v;
    }
  }
  #pragma unroll
  for (int off = 1; off < 32; off <<= 1){
    #pragma unroll
    for (int o = 0; o < 8; ++o){
      sv[o] += __shfl_xor(sv[o], off);
      sq[o] += __shfl_xor(sq[o], off);
    }
  }
  if (sg == 0){
    #pragma unroll
    for (int o = 0; o < 8; ++o){
      int ch = og * 8 + o;
      part[(size_t)(ch * 2) * 4096 + blk]     = sv[o];
      part[(size_t)(ch * 2 + 1) * 4096 + blk] = sq[o];
    }
  }
}

// ---------------- mlp1: f32 VALU pass (gather phi-psi, BN0+ReLU, W1, h1+stats)
template<int CIN, int COUT>
__global__ __launch_bounds__(256) void mlp1_pass(
    const float* __restrict__ phi, const float* __restrict__ psi,
    const int* __restrict__ gi, const float* __restrict__ bnin,
    const float* __restrict__ W,
    unsigned short* __restrict__ hout, float* __restrict__ part)
{
  constexpr int OPT = COUT / 8;
  __shared__ __align__(16) float Wt[CIN][COUT];
  __shared__ __align__(16) float ft[CIN][128];
  const int tid = threadIdx.x, blk = blockIdx.x;
  const size_t s0 = (size_t)blk * 128;

  for (int i = tid; i < CIN * COUT; i += 256){
    int o = i / CIN, c = i - o * CIN;
    Wt[c][o] = W[i];
  }
  {
    __shared__ int gidx[128];
    __shared__ float psm[4][64];
    const int b  = (int)(s0 >> 15);
    const int m0 = ((int)(s0 & 32767)) >> 5;
    if (tid < 128) gidx[tid] = gi[(size_t)b * 32768 + (size_t)m0 * K_ + tid];
    psm[tid >> 6][tid & 63] =
        psi[((size_t)b * M_ + m0 + (tid >> 6)) * 64 + (tid & 63)];
    __syncthreads();
    const int sl = tid >> 1, half = tid & 1;
    const int g = gidx[sl];
    const int mi = sl >> 5;
    const float* gp = phi + ((size_t)b * N_ + g) * 64 + half * 32;
    #pragma unroll
    for (int j = 0; j < 8; ++j){
      float4 v = *reinterpret_cast<const float4*>(gp + j * 4);
      int c = half * 32 + j * 4;
      ft[c][sl]     = fmaxf((v.x - psm[mi][c])     * bnin[c]     + bnin[CIN + c],     0.0f);
      ft[c + 1][sl] = fmaxf((v.y - psm[mi][c + 1]) * bnin[c + 1] + bnin[CIN + c + 1], 0.0f);
      ft[c + 2][sl] = fmaxf((v.z - psm[mi][c + 2]) * bnin[c + 2] + bnin[CIN + c + 2], 0.0f);
      ft[c + 3][sl] = fmaxf((v.w - psm[mi][c + 3]) * bnin[c + 3] + bnin[CIN + c + 3], 0.0f);
    }
  }
  __syncthreads();

  const int sg = tid & 31, og = tid >> 5;
  float acc[4][OPT];
  #pragma unroll
  for (int i = 0; i < 4; ++i)
    #pragma unroll
    for (int o = 0; o < OPT; ++o) acc[i][o] = 0.0f;

  #pragma unroll 2
  for (int c = 0; c < CIN; ++c){
    float4 f = *reinterpret_cast<const float4*>(&ft[c][sg * 4]);
    float4 w[OPT / 4];
    #pragma unroll
    for (int j = 0; j < OPT / 4; ++j)
      w[j] = *reinterpret_cast<const float4*>(&Wt[c][og * OPT + j * 4]);
    const float fv[4] = {f.x, f.y, f.z, f.w};
    #pragma unroll
    for (int i = 0; i < 4; ++i){
      #pragma unroll
      for (int j = 0; j < OPT / 4; ++j){
        acc[i][j * 4 + 0] += fv[i] * w[j].x;
        acc[i][j * 4 + 1] += fv[i] * w[j].y;
        acc[i][j * 4 + 2] += fv[i] * w[j].z;
        acc[i][j * 4 + 3] += fv[i] * w[j].w;
      }
    }
  }

  #pragma unroll
  for (int i = 0; i < 4; ++i){
    size_t s = s0 + sg * 4 + i;
    unsigned pk[OPT / 2];
    #pragma unroll
    for (int o = 0; o < OPT / 2; ++o)
      pk[o] = f2bf(acc[i][2 * o]) | (f2bf(acc[i][2 * o + 1]) << 16);
    uint4* dst = reinterpret_cast<uint4*>(hout + s * COUT + og * OPT);
    dst[0] = make_uint4(pk[0], pk[1], pk[2], pk[3]);
  }
  float sv[OPT], sq[OPT];
  #pragma unroll
  for (int o = 0; o < OPT; ++o){
    float a0 = acc[0][o], a1 = acc[1][o], a2 = acc[2][o], a3 = acc[3][o];
    sv[o] = ((a0 + a1) + a2) + a3;
    sq[o] = ((a0 * a0 + a1 * a1) + a2 * a2) + a3 * a3;
  }
  #pragma unroll
  for (int off = 1; off < 32; off <<= 1){
    #pragma unroll
    for (int o = 0; o < OPT; ++o){
      sv[o] += __shfl_xor(sv[o], off);
      sq[o] += __shfl_xor(sq[o], off);
    }
  }
  if (sg == 0){
    #pragma unroll
    for (int o = 0; o < OPT; ++o){
      int ch = og * OPT + o;
      part[(size_t)(ch * 2) * 4096 + blk]     = sv[o];
      part[(size_t)(ch * 2 + 1) * 4096 + blk] = sq[o];
    }
  }
}

// ---------------- mlp2 via MFMA (split-bf16, 3-term) ------------------------
// h2[s][o] = sum_c f[s][c]*W2[o][c]; f,W split hi/lo bf16; AhBh+AhBl+AlBh.
// Fragment layouts (mfma_f32_16x16x32_bf16): A row=l&15, k=(l>>4)*8+j;
// B col=l&15, same k; D col=l&15, row=(l>>4)*4+reg [guide §3, m89-verified].
__global__ __launch_bounds__(256) void mlp2_mfma(
    const unsigned short* __restrict__ h1, const float* __restrict__ bn1,
    const float* __restrict__ W2, float* __restrict__ part,
    float* __restrict__ mxmn)
{
  __shared__ unsigned short wsh[128 * 72], wsl[128 * 72];
  __shared__ unsigned short fsh[128 * 72], fsl[128 * 72];
  const int tid = threadIdx.x, blk = blockIdx.x;
  const size_t s0 = (size_t)blk * 128;

  // stage W2 hi/lo
  for (int i = tid; i < 128 * 64; i += 256){
    int o = i >> 6, c = i & 63;
    float f = W2[i];
    unsigned hb = f2bf(f);
    float res = f - bf2f((unsigned short)hb);
    wsh[o * 72 + c] = (unsigned short)hb;
    wsl[o * 72 + c] = (unsigned short)f2bf(res);
  }
  // stage f = relu(bn1(h1)) hi/lo
  {
    const int sl = tid >> 1, c0 = (tid & 1) * 32;
    const unsigned short* hp = h1 + (s0 + sl) * 64 + c0;
    #pragma unroll
    for (int j = 0; j < 4; ++j){
      ushort8 raw = *reinterpret_cast<const ushort8*>(hp + j * 8);
      ushort8 ph, pl;
      #pragma unroll
      for (int e = 0; e < 8; ++e){
        int c = c0 + j * 8 + e;
        float f = fmaxf(bf2f(raw[e]) * bn1[c] + bn1[64 + c], 0.0f);
        unsigned hb = f2bf(f);
        float res = f - bf2f((unsigned short)hb);
        ph[e] = (unsigned short)hb;
        pl[e] = (unsigned short)f2bf(res);
      }
      *reinterpret_cast<ushort8*>(&fsh[sl * 72 + c0 + j * 8]) = ph;
      *reinterpret_cast<ushort8*>(&fsl[sl * 72 + c0 + j * 8]) = pl;
    }
  }
  __syncthreads();

  const int l = tid & 63, w = tid >> 6;
  const int col = l & 15, g = l >> 4;

  // B fragments (2 o-tiles per wave x 2 k-steps), hi/lo
  bf16x8 bh[2][2], bl[2][2];
  #pragma unroll
  for (int ot = 0; ot < 2; ++ot)
    #pragma unroll
    for (int ks = 0; ks < 2; ++ks){
      int a = (w * 32 + ot * 16 + col) * 72 + ks * 32 + g * 8;
      bh[ot][ks] = *reinterpret_cast<const bf16x8*>(&wsh[a]);
      bl[ot][ks] = *reinterpret_cast<const bf16x8*>(&wsl[a]);
    }

  f32x4v acc[8][2];
  #pragma unroll
  for (int st = 0; st < 8; ++st)
    #pragma unroll
    for (int ot = 0; ot < 2; ++ot)
      acc[st][ot] = (f32x4v){0.f, 0.f, 0.f, 0.f};

  #pragma unroll
  for (int st = 0; st < 8; ++st){
    bf16x8 ah[2], al[2];
    #pragma unroll
    for (int ks = 0; ks < 2; ++ks){
      int a = (st * 16 + col) * 72 + ks * 32 + g * 8;
      ah[ks] = *reinterpret_cast<const bf16x8*>(&fsh[a]);
      al[ks] = *reinterpret_cast<const bf16x8*>(&fsl[a]);
    }
    #pragma unroll
    for (int ot = 0; ot < 2; ++ot){
      #pragma unroll
      for (int ks = 0; ks < 2; ++ks){
        acc[st][ot] = __builtin_amdgcn_mfma_f32_16x16x32_bf16(ah[ks], bh[ot][ks], acc[st][ot], 0, 0, 0);
        acc[st][ot] = __builtin_amdgcn_mfma_f32_16x16x32_bf16(ah[ks], bl[ot][ks], acc[st][ot], 0, 0, 0);
        acc[st][ot] = __builtin_amdgcn_mfma_f32_16x16x32_bf16(al[ks], bh[ot][ks], acc[st][ot], 0, 0, 0);
      }
    }
  }

  // epilogue: stats (sum, sumsq over 128 samples) + per-m (32-sample) max/min
  #pragma unroll
  for (int ot = 0; ot < 2; ++ot){
    const int ch = w * 32 + ot * 16 + col;
    float sv = 0.f, sq = 0.f;
    float mxm[4], mnm[4];
    #pragma unroll
    for (int j = 0; j < 4; ++j){ mxm[j] = -1e30f; mnm[j] = 1e30f; }
    #pragma unroll
    for (int st = 0; st < 8; ++st){
      f32x4v a = acc[st][ot];
      float t0 = a[0], t1 = a[1], t2 = a[2], t3 = a[3];
      sv += ((t0 + t1) + t2) + t3;
      sq += ((t0 * t0 + t1 * t1) + t2 * t2) + t3 * t3;
      float tmx = fmaxf(fmaxf(t0, t1), fmaxf(t2, t3));
      float tmn = fminf(fminf(t0, t1), fminf(t2, t3));
      mxm[st >> 1] = fmaxf(mxm[st >> 1], tmx);
      mnm[st >> 1] = fminf(mnm[st >> 1], tmn);
    }
    sv += __shfl_xor(sv, 16); sv += __shfl_xor(sv, 32);
    sq += __shfl_xor(sq, 16); sq += __shfl_xor(sq, 32);
    #pragma unroll
    for (int j = 0; j < 4; ++j){
      mxm[j] = fmaxf(mxm[j], __shfl_xor(mxm[j], 16));
      mxm[j] = fmaxf(mxm[j], __shfl_xor(mxm[j], 32));
      mnm[j] = fminf(mnm[j], __shfl_xor(mnm[j], 16));
      mnm[j] = fminf(mnm[j], __shfl_xor(mnm[j], 32));
    }
    if (g == 0){
      part[(size_t)(ch * 2) * 4096 + blk]     = sv;
      part[(size_t)(ch * 2 + 1) * 4096 + blk] = sq;
      #pragma unroll
      for (int j = 0; j < 4; ++j){
        size_t mf = (s0 >> 5) + j;
        mxmn[mf * 128 + ch]          = mxm[j];
        mxmn[MF_TOT + mf * 128 + ch] = mnm[j];
      }
    }
  }
}

// ---------------- BN stats reduce + scale/shift -----------------------------
__global__ __launch_bounds__(256) void reduce_stats(const float* __restrict__ part,
                                                    const float* __restrict__ g,
                                                    const float* __restrict__ bb,
                                                    float* __restrict__ bn, int cout){
  const int ch = blockIdx.x, tid = threadIdx.x;
  float s = 0.f, q = 0.f;
  const float* ps = part + (size_t)(ch * 2) * 4096;
  const float* pq = part + (size_t)(ch * 2 + 1) * 4096;
  for (int i = tid; i < 4096; i += 256){ s += ps[i]; q += pq[i]; }
  #pragma unroll
  for (int off = 1; off < 64; off <<= 1){ s += __shfl_xor(s, off); q += __shfl_xor(q, off); }
  __shared__ float as_[4], aq_[4];
  if ((tid & 63) == 0){ as_[tid >> 6] = s; aq_[tid >> 6] = q; }
  __syncthreads();
  if (tid == 0){
    float S = as_[0] + as_[1] + as_[2] + as_[3];
    float Q = aq_[0] + aq_[1] + aq_[2] + aq_[3];
    const float cnt = 524288.0f;
    float mean = S / cnt;
    float var  = Q / cnt - mean * mean;
    float sc = g[ch] / sqrtf(var + 1e-5f);
    bn[ch] = sc;
    bn[cout + ch] = bb[ch] - mean * sc;
  }
}

// ---------------- finish: out = relu(max(a*mx+sh, a*mn+sh)) -----------------
__global__ __launch_bounds__(256) void bn_minmax_finish(const float* __restrict__ mxmn,
                                                        const float* __restrict__ bn2,
                                                        float* __restrict__ out){
  const int i = blockIdx.x * 256 + threadIdx.x;
  const int ch = i & 127;
  const float a = bn2[ch], sh = bn2[128 + ch];
  const float mx = mxmn[i], mn = mxmn[MF_TOT + i];
  out[i] = fmaxf(fmaxf(mx * a + sh, mn * a + sh), 0.0f);
}

extern "C" void kernel_launch(void* const* d_in, const int* in_sizes, int n_in,
                              void* d_out, int out_size, void* d_ws, size_t ws_size,
                              hipStream_t stream){
  (void)in_sizes; (void)n_in; (void)out_size; (void)ws_size;
  const float* xyz    = (const float*)d_in[0];
  const float* points = (const float*)d_in[1];
  const float* W0 = (const float*)d_in[2];
  const float* g0 = (const float*)d_in[3];
  const float* b0 = (const float*)d_in[4];
  const float* W1 = (const float*)d_in[5];
  const float* g1 = (const float*)d_in[6];
  const float* b1 = (const float*)d_in[7];
  const float* W2 = (const float*)d_in[8];
  const float* g2 = (const float*)d_in[9];
  const float* b2 = (const float*)d_in[10];

  float* out = (float*)d_out;
  float* o_newxyz = out;
  float* o_newpts = out + (size_t)B_ * M_ * 3;
  float* o_gind   = out + (size_t)B_ * M_ * 3 + (size_t)B_ * M_ * 128;

  char* ws = (char*)d_ws;
  int*   gi   = (int*)(ws + 0);                          // 2 MB
  float* part = (float*)(ws + (2ull << 20));             // 4 MB
  float* bn0  = (float*)(ws + (6ull << 20));
  float* bn1  = (float*)(ws + (6ull << 20) + 1024);
  float* bn2  = (float*)(ws + (6ull << 20) + 2048);
  float* phi  = (float*)(ws + (8ull << 20));             // 16 MB
  float* psi  = (float*)(ws + (24ull << 20));            // 4 MB
  unsigned short* h1 = (unsigned short*)(ws + (28ull << 20));   // 64 MB
  float* mxmn = (float*)(ws + (92ull << 20));            // 16 MB

  phi_kernel<<<512, 256, 0, stream>>>(xyz, points, W0, phi);
  fps_kernel<<<16, 512, 0, stream>>>(xyz, o_newxyz);
  ballq_psi_kernel<<<4160, 256, 0, stream>>>(xyz, o_newxyz, gi, o_gind, W0, psi);

  stats0_kernel<<<4096, 256, 0, stream>>>(phi, psi, gi, part);
  reduce_stats<<<64, 256, 0, stream>>>(part, g0, b0, bn0, 64);

  mlp1_pass<64, 64><<<4096, 256, 0, stream>>>(phi, psi, gi, bn0, W1, h1, part);
  reduce_stats<<<64, 256, 0, stream>>>(part, g1, b1, bn1, 64);

  mlp2_mfma<<<4096, 256, 0, stream>>>(h1, bn1, W2, part, mxmn);
  reduce_stats<<<128, 256, 0, stream>>>(part, g2, b2, bn2, 128);
  bn_minmax_finish<<<MF_TOT / 256, 256, 0, stream>>>(mxmn, bn2, o_newpts);
}

// Round 13
// 905.098 us; speedup vs baseline: 1.2123x; 1.0363x over previous
//
#include <hip/hip_runtime.h>
#include <hip/hip_bf16.h>
#include <cstdint>

#define B_ 16
#define N_ 4096
#define CPTS_ 64
#define M_ 1024
#define K_ 32
#define MF_TOT 2097152   // B_*M_*128 pooled outputs

using ushort8 = __attribute__((ext_vector_type(8))) unsigned short;
using bf16x8  = __attribute__((ext_vector_type(8))) short;
using f32x4v  = __attribute__((ext_vector_type(4))) float;

static __device__ __forceinline__ unsigned f2bf(float x){
  unsigned u = __float_as_uint(x);
  return (u + 0x7fffu + ((u >> 16) & 1u)) >> 16;   // RTNE
}
static __device__ __forceinline__ float bf2f(unsigned short u){
  return __uint_as_float(((unsigned)u) << 16);
}

// DPP max step: v = max(v, dpp_shift(v)). Values are >= 0 so 0-fill is identity.
#define DPPMAX(v, ctrl)                                                        \
  do {                                                                         \
    int _t = __builtin_amdgcn_update_dpp(0, __float_as_int(v), (ctrl), 0xf,    \
                                         0xf, true);                           \
    (v) = fmaxf((v), __int_as_float(_t));                                      \
  } while (0)

// One distance update, all indices compile-time constant (named float4 comps).
#define STEP(MD, PX, PY, PZ, C, J)                                             \
  { float dx = PX.C - cx, dy = PY.C - cy, dz = PZ.C - cz;                      \
    float d = dx * dx; d = d + dy * dy; d = d + dz * dz;                       \
    float nm = fminf(MD.C, d); MD.C = nm;                                      \
    if (nm > bv){ bv = nm; bj = (J); } }
#define STEP4(MD, PX, PY, PZ, J0)                                              \
  STEP(MD, PX, PY, PZ, x, J0)                                                  \
  STEP(MD, PX, PY, PZ, y, (J0) + 1)                                            \
  STEP(MD, PX, PY, PZ, z, (J0) + 2)                                            \
  STEP(MD, PX, PY, PZ, w, (J0) + 3)

// ---------------- FPS: R7 exchange verbatim (670 us, proven floor) ----------
__global__ __launch_bounds__(512, 1) void fps_kernel(const float* __restrict__ xyz,
                                                     float* __restrict__ newxyz){
#pragma clang fp contract(off)
  __shared__ float xs[N_], ys[N_], zs[N_];
  __shared__ int inds_s[M_];
  __shared__ unsigned long long sv_[2][8];
  const int b = blockIdx.x, tid = threadIdx.x;
  const int lane = tid & 63, wv = tid >> 6;
  const float* xb = xyz + (size_t)b * N_ * 3;
  for (int i = tid; i < N_ * 3; i += 512){
    float v = xb[i];
    int n = i / 3, c = i - n * 3;
    if (c == 0) xs[n] = v; else if (c == 1) ys[n] = v; else zs[n] = v;
  }
  __syncthreads();
  const float4 px0 = *reinterpret_cast<const float4*>(&xs[tid * 8 + 0]);
  const float4 px1 = *reinterpret_cast<const float4*>(&xs[tid * 8 + 4]);
  const float4 py0 = *reinterpret_cast<const float4*>(&ys[tid * 8 + 0]);
  const float4 py1 = *reinterpret_cast<const float4*>(&ys[tid * 8 + 4]);
  const float4 pz0 = *reinterpret_cast<const float4*>(&zs[tid * 8 + 0]);
  const float4 pz1 = *reinterpret_cast<const float4*>(&zs[tid * 8 + 4]);
  float4 md0 = make_float4(1e10f, 1e10f, 1e10f, 1e10f);
  float4 md1 = md0;
  int far = 0;
  float cx = xs[0], cy = ys[0], cz = zs[0];
  for (int m = 0; m < M_; ++m){
    if (tid == 0) inds_s[m] = far;
    float bv = -1.0f; int bj = 0;
    STEP4(md0, px0, py0, pz0, 0)
    STEP4(md1, px1, py1, pz1, 4)
    float wm = bv;
    DPPMAX(wm, 0x111);  // row_shr:1
    DPPMAX(wm, 0x112);  // row_shr:2
    DPPMAX(wm, 0x114);  // row_shr:4
    DPPMAX(wm, 0x118);  // row_shr:8
    DPPMAX(wm, 0x142);  // row_bcast:15
    DPPMAX(wm, 0x143);  // row_bcast:31
    const float wmax = __int_as_float(
        __builtin_amdgcn_readlane(__float_as_int(wm), 63));
    unsigned long long tied = __ballot(bv == wmax);
    const int winlane = (int)__builtin_ctzll(tied);
    const int sl = m & 1;
    if (lane == winlane){
      int wn = tid * 8 + bj;
      sv_[sl][wv] = ((unsigned long long)__float_as_uint(wmax) << 32)
                  | (unsigned)(4095 - wn);     // (4095-n): smaller n wins on tie
    }
    __syncthreads();
    unsigned long long p0 = sv_[sl][0], p1 = sv_[sl][1], p2 = sv_[sl][2], p3 = sv_[sl][3];
    unsigned long long p4 = sv_[sl][4], p5 = sv_[sl][5], p6 = sv_[sl][6], p7 = sv_[sl][7];
    if (p1 > p0) p0 = p1;
    if (p3 > p2) p2 = p3;
    if (p5 > p4) p4 = p5;
    if (p7 > p6) p6 = p7;
    if (p2 > p0) p0 = p2;
    if (p6 > p4) p4 = p6;
    if (p4 > p0) p0 = p4;
    far = 4095 - (int)(p0 & 0xffffffffu);
    cx = xs[far]; cy = ys[far]; cz = zs[far];   // broadcast LDS reads
  }
  __syncthreads();
  for (int t = tid; t < M_; t += 512){
    int id = inds_s[t];
    size_t o = ((size_t)b * M_ + t) * 3;
    newxyz[o] = xs[id]; newxyz[o + 1] = ys[id]; newxyz[o + 2] = zs[id];
  }
}

// ---------------- phi: per-point layer-0 matmul (no gather) -----------------
__global__ __launch_bounds__(256) void phi_kernel(const float* __restrict__ xyz,
                                                  const float* __restrict__ points,
                                                  const float* __restrict__ W,
                                                  float* __restrict__ phi){
  __shared__ __align__(16) float Wt[67][64];
  __shared__ __align__(16) float ft[67][128];
  const int tid = threadIdx.x, blk = blockIdx.x;
  const int p0 = blk * 128;
  for (int i = tid; i < 67 * 64; i += 256){
    int o = i / 67, c = i - o * 67;
    Wt[c][o] = W[i];
  }
  const int sl = tid >> 1, half = tid & 1;
  const int p = p0 + sl;
  const float* ps = points + (size_t)p * CPTS_ + half * 32;
  #pragma unroll
  for (int j = 0; j < 8; ++j){
    float4 v = *reinterpret_cast<const float4*>(ps + j * 4);
    int c = 3 + half * 32 + j * 4;
    ft[c][sl] = v.x; ft[c + 1][sl] = v.y; ft[c + 2][sl] = v.z; ft[c + 3][sl] = v.w;
  }
  if (half == 0){
    const float* xp = xyz + (size_t)p * 3;
    ft[0][sl] = xp[0]; ft[1][sl] = xp[1]; ft[2][sl] = xp[2];
  }
  __syncthreads();
  const int sg = tid & 31, og = tid >> 5;
  float acc[4][8];
  #pragma unroll
  for (int i = 0; i < 4; ++i)
    #pragma unroll
    for (int o = 0; o < 8; ++o) acc[i][o] = 0.0f;
  #pragma unroll 2
  for (int c = 0; c < 67; ++c){
    float4 f = *reinterpret_cast<const float4*>(&ft[c][sg * 4]);
    float4 w0 = *reinterpret_cast<const float4*>(&Wt[c][og * 8]);
    float4 w1 = *reinterpret_cast<const float4*>(&Wt[c][og * 8 + 4]);
    const float fv[4] = {f.x, f.y, f.z, f.w};
    #pragma unroll
    for (int i = 0; i < 4; ++i){
      acc[i][0] += fv[i] * w0.x; acc[i][1] += fv[i] * w0.y;
      acc[i][2] += fv[i] * w0.z; acc[i][3] += fv[i] * w0.w;
      acc[i][4] += fv[i] * w1.x; acc[i][5] += fv[i] * w1.y;
      acc[i][6] += fv[i] * w1.z; acc[i][7] += fv[i] * w1.w;
    }
  }
  #pragma unroll
  for (int i = 0; i < 4; ++i){
    float* dst = phi + (size_t)(p0 + sg * 4 + i) * 64 + og * 8;
    *reinterpret_cast<float4*>(dst)     = make_float4(acc[i][0], acc[i][1], acc[i][2], acc[i][3]);
    *reinterpret_cast<float4*>(dst + 4) = make_float4(acc[i][4], acc[i][5], acc[i][6], acc[i][7]);
  }
}

// ---------------- Ball query (blocks 0..4095) + psi (blocks 4096..4159) -----
__global__ __launch_bounds__(256) void ballq_psi_kernel(const float* __restrict__ xyz,
                                                        const float* __restrict__ newxyz,
                                                        int* __restrict__ gi,
                                                        float* __restrict__ gif,
                                                        const float* __restrict__ W0,
                                                        float* __restrict__ psi){
  if (blockIdx.x >= 4096){
    const int mi = (blockIdx.x - 4096) * 256 + threadIdx.x;
    const float x = newxyz[(size_t)mi * 3];
    const float y = newxyz[(size_t)mi * 3 + 1];
    const float z = newxyz[(size_t)mi * 3 + 2];
    float* dst = psi + (size_t)mi * 64;
    #pragma unroll
    for (int o4 = 0; o4 < 16; ++o4){
      float v[4];
      #pragma unroll
      for (int e = 0; e < 4; ++e){
        int o = o4 * 4 + e;
        v[e] = fmaf(z, W0[o * 67 + 2], fmaf(y, W0[o * 67 + 1], x * W0[o * 67]));
      }
      *reinterpret_cast<float4*>(dst + o4 * 4) = make_float4(v[0], v[1], v[2], v[3]);
    }
    return;
  }
  const int gw = (blockIdx.x * 256 + threadIdx.x) >> 6;
  const int lane = threadIdx.x & 63;
  const int b = gw >> 10, m = gw & 1023;
  const float* xb = xyz + (size_t)b * N_ * 3;
  const size_t no = (size_t)b * M_ + m;
  const float cx = newxyz[no * 3], cy = newxyz[no * 3 + 1], cz = newxyz[no * 3 + 2];
  const float sm = fmaf(cz, cz, fmaf(cy, cy, cx * cx));
  int total = 0, first_idx = 0; bool havef = false;
  int*   gd = gi  + no * K_;
  float* fd = gif + no * K_;
  for (int ch = 0; ch < 64 && total < K_; ++ch){
    const int n = ch * 64 + lane;
    const float x = xb[n * 3], y = xb[n * 3 + 1], z = xb[n * 3 + 2];
    const float sn = fmaf(z, z, fmaf(y, y, x * x));
    const float dt = fmaf(z, cz, fmaf(y, cy, x * cx));
    float d2 = (sm + sn) - 2.0f * dt;                 // ref: |a|^2+|b|^2-2ab
    float dist = sqrtf(fmaxf(d2, 0.0f));
    bool pred = !(dist > 0.2f);
    unsigned long long mask = __ballot(pred);
    if (!havef && mask){ havef = true; first_idx = ch * 64 + (int)__builtin_ctzll(mask); }
    if (pred){
      int rank = total + (int)__popcll(mask & ((1ull << lane) - 1ull));
      if (rank < K_){ gd[rank] = n; fd[rank] = (float)n; }
    }
    total += (int)__popcll(mask);
  }
  if (total < K_ && lane >= total && lane < K_){ gd[lane] = first_idx; fd[lane] = (float)first_idx; }
}

// ---------------- stats0: BN0 sums over gathered (phi - psi) ----------------
__global__ __launch_bounds__(256) void stats0_kernel(const float* __restrict__ phi,
                                                     const float* __restrict__ psi,
                                                     const int* __restrict__ gi,
                                                     float* __restrict__ part){
  __shared__ int gidx[128];
  __shared__ float psm[4][64];
  const int tid = threadIdx.x, blk = blockIdx.x;
  const size_t s0 = (size_t)blk * 128;
  const int b  = (int)(s0 >> 15);
  const int m0 = ((int)(s0 & 32767)) >> 5;
  if (tid < 128) gidx[tid] = gi[(size_t)b * 32768 + (size_t)m0 * K_ + tid];
  psm[tid >> 6][tid & 63] =
      psi[((size_t)b * M_ + m0 + (tid >> 6)) * 64 + (tid & 63)];
  __syncthreads();
  const int sg = tid & 31, og = tid >> 5;
  const int mi = sg >> 3;
  float sv[8], sq[8];
  #pragma unroll
  for (int o = 0; o < 8; ++o){ sv[o] = 0.f; sq[o] = 0.f; }
  #pragma unroll
  for (int i = 0; i < 4; ++i){
    const int g = gidx[sg * 4 + i];
    const float* gp = phi + ((size_t)b * N_ + g) * 64 + og * 8;
    float4 a0 = *reinterpret_cast<const float4*>(gp);
    float4 a1 = *reinterpret_cast<const float4*>(gp + 4);
    const float pv[8] = {a0.x, a0.y, a0.z, a0.w, a1.x, a1.y, a1.z, a1.w};
    #pragma unroll
    for (int o = 0; o < 8; ++o){
      float v = pv[o] - psm[mi][og * 8 + o];
      sv[o] += v; sq[o] += v * v;
    }
  }
  #pragma unroll
  for (int off = 1; off < 32; off <<= 1){
    #pragma unroll
    for (int o = 0; o < 8; ++o){
      sv[o] += __shfl_xor(sv[o], off);
      sq[o] += __shfl_xor(sq[o], off);
    }
  }
  if (sg == 0){
    #pragma unroll
    for (int o = 0; o < 8; ++o){
      int ch = og * 8 + o;
      part[(size_t)(ch * 2) * 4096 + blk]     = sv[o];
      part[(size_t)(ch * 2 + 1) * 4096 + blk] = sq[o];
    }
  }
}

// ---------------- mlp1 via MFMA (split-bf16, 3-term) ------------------------
// h1[s][o] = sum_c f[s][c]*W1[o][c], f = relu(BN0(phi[g]-psi[m])).
// Same fragment scheme as mlp2_mfma (R12-verified). 4 waves x 1 o-tile.
__global__ __launch_bounds__(256) void mlp1_mfma(
    const float* __restrict__ phi, const float* __restrict__ psi,
    const int* __restrict__ gi, const float* __restrict__ bn0,
    const float* __restrict__ W1,
    unsigned short* __restrict__ h1, float* __restrict__ part)
{
  __shared__ unsigned short wsh[64 * 72], wsl[64 * 72];
  __shared__ unsigned short fsh[128 * 72], fsl[128 * 72];
  __shared__ int gidx[128];
  __shared__ float psm[4][64];
  const int tid = threadIdx.x, blk = blockIdx.x;
  const size_t s0 = (size_t)blk * 128;
  const int b  = (int)(s0 >> 15);
  const int m0 = ((int)(s0 & 32767)) >> 5;

  // stage W1 hi/lo
  for (int i = tid; i < 64 * 64; i += 256){
    int o = i >> 6, c = i & 63;
    float f = W1[i];
    unsigned hb = f2bf(f);
    float res = f - bf2f((unsigned short)hb);
    wsh[o * 72 + c] = (unsigned short)hb;
    wsl[o * 72 + c] = (unsigned short)f2bf(res);
  }
  if (tid < 128) gidx[tid] = gi[(size_t)b * 32768 + (size_t)m0 * K_ + tid];
  psm[tid >> 6][tid & 63] =
      psi[((size_t)b * M_ + m0 + (tid >> 6)) * 64 + (tid & 63)];
  __syncthreads();
  // stage f = relu(BN0(phi[g]-psi)) hi/lo (gathered)
  {
    const int sl = tid >> 1, half = tid & 1;
    const int g = gidx[sl];
    const int mi = sl >> 5;
    const float* gp = phi + ((size_t)b * N_ + g) * 64 + half * 32;
    #pragma unroll
    for (int jj = 0; jj < 4; ++jj){
      float4 v0 = *reinterpret_cast<const float4*>(gp + jj * 8);
      float4 v1 = *reinterpret_cast<const float4*>(gp + jj * 8 + 4);
      const float vv[8] = {v0.x, v0.y, v0.z, v0.w, v1.x, v1.y, v1.z, v1.w};
      ushort8 ph, pl;
      #pragma unroll
      for (int e = 0; e < 8; ++e){
        int c = half * 32 + jj * 8 + e;
        float f = fmaxf((vv[e] - psm[mi][c]) * bn0[c] + bn0[64 + c], 0.0f);
        unsigned hb = f2bf(f);
        float res = f - bf2f((unsigned short)hb);
        ph[e] = (unsigned short)hb;
        pl[e] = (unsigned short)f2bf(res);
      }
      *reinterpret_cast<ushort8*>(&fsh[sl * 72 + half * 32 + jj * 8]) = ph;
      *reinterpret_cast<ushort8*>(&fsl[sl * 72 + half * 32 + jj * 8]) = pl;
    }
  }
  __syncthreads();

  const int l = tid & 63, w = tid >> 6;
  const int col = l & 15, g4 = l >> 4;
  const int ch = w * 16 + col;

  // B fragments (1 o-tile per wave x 2 k-steps), hi/lo
  bf16x8 bh[2], bl[2];
  #pragma unroll
  for (int ks = 0; ks < 2; ++ks){
    int a = ch * 72 + ks * 32 + g4 * 8;
    bh[ks] = *reinterpret_cast<const bf16x8*>(&wsh[a]);
    bl[ks] = *reinterpret_cast<const bf16x8*>(&wsl[a]);
  }

  f32x4v acc[8];
  #pragma unroll
  for (int st = 0; st < 8; ++st) acc[st] = (f32x4v){0.f, 0.f, 0.f, 0.f};

  #pragma unroll
  for (int st = 0; st < 8; ++st){
    #pragma unroll
    for (int ks = 0; ks < 2; ++ks){
      int a = (st * 16 + col) * 72 + ks * 32 + g4 * 8;
      bf16x8 ah = *reinterpret_cast<const bf16x8*>(&fsh[a]);
      bf16x8 al = *reinterpret_cast<const bf16x8*>(&fsl[a]);
      acc[st] = __builtin_amdgcn_mfma_f32_16x16x32_bf16(ah, bh[ks], acc[st], 0, 0, 0);
      acc[st] = __builtin_amdgcn_mfma_f32_16x16x32_bf16(ah, bl[ks], acc[st], 0, 0, 0);
      acc[st] = __builtin_amdgcn_mfma_f32_16x16x32_bf16(al, bh[ks], acc[st], 0, 0, 0);
    }
  }

  // h1 store (bf16) from D fragments: sample = s0 + st*16 + g4*4 + reg
  #pragma unroll
  for (int st = 0; st < 8; ++st){
    size_t sbase = s0 + st * 16 + g4 * 4;
    #pragma unroll
    for (int r = 0; r < 4; ++r)
      h1[(sbase + r) * 64 + ch] = (unsigned short)f2bf(acc[st][r]);
  }

  // BN1 partial stats (sum, sumsq over 128 samples per channel)
  float sv = 0.f, sq = 0.f;
  #pragma unroll
  for (int st = 0; st < 8; ++st){
    f32x4v a = acc[st];
    float t0 = a[0], t1 = a[1], t2 = a[2], t3 = a[3];
    sv += ((t0 + t1) + t2) + t3;
    sq += ((t0 * t0 + t1 * t1) + t2 * t2) + t3 * t3;
  }
  sv += __shfl_xor(sv, 16); sv += __shfl_xor(sv, 32);
  sq += __shfl_xor(sq, 16); sq += __shfl_xor(sq, 32);
  if (g4 == 0){
    part[(size_t)(ch * 2) * 4096 + blk]     = sv;
    part[(size_t)(ch * 2 + 1) * 4096 + blk] = sq;
  }
}

// ---------------- mlp2 via MFMA (split-bf16, 3-term) — R12-verified ---------
__global__ __launch_bounds__(256) void mlp2_mfma(
    const unsigned short* __restrict__ h1, const float* __restrict__ bn1,
    const float* __restrict__ W2, float* __restrict__ part,
    float* __restrict__ mxmn)
{
  __shared__ unsigned short wsh[128 * 72], wsl[128 * 72];
  __shared__ unsigned short fsh[128 * 72], fsl[128 * 72];
  const int tid = threadIdx.x, blk = blockIdx.x;
  const size_t s0 = (size_t)blk * 128;

  for (int i = tid; i < 128 * 64; i += 256){
    int o = i >> 6, c = i & 63;
    float f = W2[i];
    unsigned hb = f2bf(f);
    float res = f - bf2f((unsigned short)hb);
    wsh[o * 72 + c] = (unsigned short)hb;
    wsl[o * 72 + c] = (unsigned short)f2bf(res);
  }
  {
    const int sl = tid >> 1, c0 = (tid & 1) * 32;
    const unsigned short* hp = h1 + (s0 + sl) * 64 + c0;
    #pragma unroll
    for (int j = 0; j < 4; ++j){
      ushort8 raw = *reinterpret_cast<const ushort8*>(hp + j * 8);
      ushort8 ph, pl;
      #pragma unroll
      for (int e = 0; e < 8; ++e){
        int c = c0 + j * 8 + e;
        float f = fmaxf(bf2f(raw[e]) * bn1[c] + bn1[64 + c], 0.0f);
        unsigned hb = f2bf(f);
        float res = f - bf2f((unsigned short)hb);
        ph[e] = (unsigned short)hb;
        pl[e] = (unsigned short)f2bf(res);
      }
      *reinterpret_cast<ushort8*>(&fsh[sl * 72 + c0 + j * 8]) = ph;
      *reinterpret_cast<ushort8*>(&fsl[sl * 72 + c0 + j * 8]) = pl;
    }
  }
  __syncthreads();

  const int l = tid & 63, w = tid >> 6;
  const int col = l & 15, g = l >> 4;

  bf16x8 bh[2][2], bl[2][2];
  #pragma unroll
  for (int ot = 0; ot < 2; ++ot)
    #pragma unroll
    for (int ks = 0; ks < 2; ++ks){
      int a = (w * 32 + ot * 16 + col) * 72 + ks * 32 + g * 8;
      bh[ot][ks] = *reinterpret_cast<const bf16x8*>(&wsh[a]);
      bl[ot][ks] = *reinterpret_cast<const bf16x8*>(&wsl[a]);
    }

  f32x4v acc[8][2];
  #pragma unroll
  for (int st = 0; st < 8; ++st)
    #pragma unroll
    for (int ot = 0; ot < 2; ++ot)
      acc[st][ot] = (f32x4v){0.f, 0.f, 0.f, 0.f};

  #pragma unroll
  for (int st = 0; st < 8; ++st){
    bf16x8 ah[2], al[2];
    #pragma unroll
    for (int ks = 0; ks < 2; ++ks){
      int a = (st * 16 + col) * 72 + ks * 32 + g * 8;
      ah[ks] = *reinterpret_cast<const bf16x8*>(&fsh[a]);
      al[ks] = *reinterpret_cast<const bf16x8*>(&fsl[a]);
    }
    #pragma unroll
    for (int ot = 0; ot < 2; ++ot){
      #pragma unroll
      for (int ks = 0; ks < 2; ++ks){
        acc[st][ot] = __builtin_amdgcn_mfma_f32_16x16x32_bf16(ah[ks], bh[ot][ks], acc[st][ot], 0, 0, 0);
        acc[st][ot] = __builtin_amdgcn_mfma_f32_16x16x32_bf16(ah[ks], bl[ot][ks], acc[st][ot], 0, 0, 0);
        acc[st][ot] = __builtin_amdgcn_mfma_f32_16x16x32_bf16(al[ks], bh[ot][ks], acc[st][ot], 0, 0, 0);
      }
    }
  }

  #pragma unroll
  for (int ot = 0; ot < 2; ++ot){
    const int ch = w * 32 + ot * 16 + col;
    float sv = 0.f, sq = 0.f;
    float mxm[4], mnm[4];
    #pragma unroll
    for (int j = 0; j < 4; ++j){ mxm[j] = -1e30f; mnm[j] = 1e30f; }
    #pragma unroll
    for (int st = 0; st < 8; ++st){
      f32x4v a = acc[st][ot];
      float t0 = a[0], t1 = a[1], t2 = a[2], t3 = a[3];
      sv += ((t0 + t1) + t2) + t3;
      sq += ((t0 * t0 + t1 * t1) + t2 * t2) + t3 * t3;
      float tmx = fmaxf(fmaxf(t0, t1), fmaxf(t2, t3));
      float tmn = fminf(fminf(t0, t1), fminf(t2, t3));
      mxm[st >> 1] = fmaxf(mxm[st >> 1], tmx);
      mnm[st >> 1] = fminf(mnm[st >> 1], tmn);
    }
    sv += __shfl_xor(sv, 16); sv += __shfl_xor(sv, 32);
    sq += __shfl_xor(sq, 16); sq += __shfl_xor(sq, 32);
    #pragma unroll
    for (int j = 0; j < 4; ++j){
      mxm[j] = fmaxf(mxm[j], __shfl_xor(mxm[j], 16));
      mxm[j] = fmaxf(mxm[j], __shfl_xor(mxm[j], 32));
      mnm[j] = fminf(mnm[j], __shfl_xor(mnm[j], 16));
      mnm[j] = fminf(mnm[j], __shfl_xor(mnm[j], 32));
    }
    if (g == 0){
      part[(size_t)(ch * 2) * 4096 + blk]     = sv;
      part[(size_t)(ch * 2 + 1) * 4096 + blk] = sq;
      #pragma unroll
      for (int j = 0; j < 4; ++j){
        size_t mf = (s0 >> 5) + j;
        mxmn[mf * 128 + ch]          = mxm[j];
        mxmn[MF_TOT + mf * 128 + ch] = mnm[j];
      }
    }
  }
}

// ---------------- BN stats reduce + scale/shift -----------------------------
__global__ __launch_bounds__(256) void reduce_stats(const float* __restrict__ part,
                                                    const float* __restrict__ g,
                                                    const float* __restrict__ bb,
                                                    float* __restrict__ bn, int cout){
  const int ch = blockIdx.x, tid = threadIdx.x;
  float s = 0.f, q = 0.f;
  const float* ps = part + (size_t)(ch * 2) * 4096;
  const float* pq = part + (size_t)(ch * 2 + 1) * 4096;
  for (int i = tid; i < 4096; i += 256){ s += ps[i]; q += pq[i]; }
  #pragma unroll
  for (int off = 1; off < 64; off <<= 1){ s += __shfl_xor(s, off); q += __shfl_xor(q, off); }
  __shared__ float as_[4], aq_[4];
  if ((tid & 63) == 0){ as_[tid >> 6] = s; aq_[tid >> 6] = q; }
  __syncthreads();
  if (tid == 0){
    float S = as_[0] + as_[1] + as_[2] + as_[3];
    float Q = aq_[0] + aq_[1] + aq_[2] + aq_[3];
    const float cnt = 524288.0f;
    float mean = S / cnt;
    float var  = Q / cnt - mean * mean;
    float sc = g[ch] / sqrtf(var + 1e-5f);
    bn[ch] = sc;
    bn[cout + ch] = bb[ch] - mean * sc;
  }
}

// ---------------- finish: out = relu(max(a*mx+sh, a*mn+sh)) -----------------
__global__ __launch_bounds__(256) void bn_minmax_finish(const float* __restrict__ mxmn,
                                                        const float* __restrict__ bn2,
                                                        float* __restrict__ out){
  const int i = blockIdx.x * 256 + threadIdx.x;
  const int ch = i & 127;
  const float a = bn2[ch], sh = bn2[128 + ch];
  const float mx = mxmn[i], mn = mxmn[MF_TOT + i];
  out[i] = fmaxf(fmaxf(mx * a + sh, mn * a + sh), 0.0f);
}

extern "C" void kernel_launch(void* const* d_in, const int* in_sizes, int n_in,
                              void* d_out, int out_size, void* d_ws, size_t ws_size,
                              hipStream_t stream){
  (void)in_sizes; (void)n_in; (void)out_size; (void)ws_size;
  const float* xyz    = (const float*)d_in[0];
  const float* points = (const float*)d_in[1];
  const float* W0 = (const float*)d_in[2];
  const float* g0 = (const float*)d_in[3];
  const float* b0 = (const float*)d_in[4];
  const float* W1 = (const float*)d_in[5];
  const float* g1 = (const float*)d_in[6];
  const float* b1 = (const float*)d_in[7];
  const float* W2 = (const float*)d_in[8];
  const float* g2 = (const float*)d_in[9];
  const float* b2 = (const float*)d_in[10];

  float* out = (float*)d_out;
  float* o_newxyz = out;
  float* o_newpts = out + (size_t)B_ * M_ * 3;
  float* o_gind   = out + (size_t)B_ * M_ * 3 + (size_t)B_ * M_ * 128;

  char* ws = (char*)d_ws;
  int*   gi   = (int*)(ws + 0);                          // 2 MB
  float* part = (float*)(ws + (2ull << 20));             // 4 MB
  float* bn0  = (float*)(ws + (6ull << 20));
  float* bn1  = (float*)(ws + (6ull << 20) + 1024);
  float* bn2  = (float*)(ws + (6ull << 20) + 2048);
  float* phi  = (float*)(ws + (8ull << 20));             // 16 MB
  float* psi  = (float*)(ws + (24ull << 20));            // 4 MB
  unsigned short* h1 = (unsigned short*)(ws + (28ull << 20));   // 64 MB
  float* mxmn = (float*)(ws + (92ull << 20));            // 16 MB

  phi_kernel<<<512, 256, 0, stream>>>(xyz, points, W0, phi);
  fps_kernel<<<16, 512, 0, stream>>>(xyz, o_newxyz);
  ballq_psi_kernel<<<4160, 256, 0, stream>>>(xyz, o_newxyz, gi, o_gind, W0, psi);

  stats0_kernel<<<4096, 256, 0, stream>>>(phi, psi, gi, part);
  reduce_stats<<<64, 256, 0, stream>>>(part, g0, b0, bn0, 64);

  mlp1_mfma<<<4096, 256, 0, stream>>>(phi, psi, gi, bn0, W1, h1, part);
  reduce_stats<<<64, 256, 0, stream>>>(part, g1, b1, bn1, 64);

  mlp2_mfma<<<4096, 256, 0, stream>>>(h1, bn1, W2, part, mxmn);
  reduce_stats<<<128, 256, 0, stream>>>(part, g2, b2, bn2, 128);
  bn_minmax_finish<<<MF_TOT / 256, 256, 0, stream>>>(mxmn, bn2, o_newpts);
}

// Round 14
// 876.343 us; speedup vs baseline: 1.2521x; 1.0328x over previous
//
#include <hip/hip_runtime.h>
#include <hip/hip_bf16.h>
#include <cstdint>

#define B_ 16
#define N_ 4096
#define CPTS_ 64
#define M_ 1024
#define K_ 32
#define MF_TOT 2097152   // B_*M_*128 pooled outputs

using ushort8 = __attribute__((ext_vector_type(8))) unsigned short;
using bf16x8  = __attribute__((ext_vector_type(8))) short;
using f32x4v  = __attribute__((ext_vector_type(4))) float;

static __device__ __forceinline__ unsigned f2bf(float x){
  unsigned u = __float_as_uint(x);
  return (u + 0x7fffu + ((u >> 16) & 1u)) >> 16;   // RTNE
}
static __device__ __forceinline__ float bf2f(unsigned short u){
  return __uint_as_float(((unsigned)u) << 16);
}

// DPP max step: v = max(v, dpp_shift(v)). Values are >= 0 so 0-fill is identity.
#define DPPMAX(v, ctrl)                                                        \
  do {                                                                         \
    int _t = __builtin_amdgcn_update_dpp(0, __float_as_int(v), (ctrl), 0xf,    \
                                         0xf, true);                           \
    (v) = fmaxf((v), __int_as_float(_t));                                      \
  } while (0)

// One distance update, all indices compile-time constant (named float4 comps).
#define STEP(MD, PX, PY, PZ, C, J)                                             \
  { float dx = PX.C - cx, dy = PY.C - cy, dz = PZ.C - cz;                      \
    float d = dx * dx; d = d + dy * dy; d = d + dz * dz;                       \
    float nm = fminf(MD.C, d); MD.C = nm;                                      \
    if (nm > bv){ bv = nm; bj = (J); } }
#define STEP4(MD, PX, PY, PZ, J0)                                              \
  STEP(MD, PX, PY, PZ, x, J0)                                                  \
  STEP(MD, PX, PY, PZ, y, (J0) + 1)                                            \
  STEP(MD, PX, PY, PZ, z, (J0) + 2)                                            \
  STEP(MD, PX, PY, PZ, w, (J0) + 3)

// ---------------- FPS: 4 waves x 16 pts, u64-only 4-slot exchange -----------
// R14: the untested cell of the {waves} x {exchange form} matrix.
// Update = R6's proven named-float4 STEP4 (n = tid*16+j, wave-contiguous);
// exchange = R7's proven u64-only slots + post-tree broadcast coord reads.
// Same per-SIMD update issue as R7 (1 wave x 192 inst); cheaper 4-wave
// barrier, 3-compare tree, 2x b128 slot reads.
__global__ __launch_bounds__(256, 1) void fps_kernel(const float* __restrict__ xyz,
                                                     float* __restrict__ newxyz){
#pragma clang fp contract(off)
  __shared__ float xs[N_], ys[N_], zs[N_];
  __shared__ int inds_s[M_];
  __shared__ unsigned long long sv_[2][4];
  const int b = blockIdx.x, tid = threadIdx.x;
  const int lane = tid & 63, wv = tid >> 6;
  const float* xb = xyz + (size_t)b * N_ * 3;
  for (int i = tid; i < N_ * 3; i += 256){
    float v = xb[i];
    int n = i / 3, c = i - n * 3;
    if (c == 0) xs[n] = v; else if (c == 1) ys[n] = v; else zs[n] = v;
  }
  __syncthreads();
  // per-lane points: n = tid*16 + j  (wave w owns [w*1024, w*1024+1024))
  const float4 px0 = *reinterpret_cast<const float4*>(&xs[tid * 16 + 0]);
  const float4 px1 = *reinterpret_cast<const float4*>(&xs[tid * 16 + 4]);
  const float4 px2 = *reinterpret_cast<const float4*>(&xs[tid * 16 + 8]);
  const float4 px3 = *reinterpret_cast<const float4*>(&xs[tid * 16 + 12]);
  const float4 py0 = *reinterpret_cast<const float4*>(&ys[tid * 16 + 0]);
  const float4 py1 = *reinterpret_cast<const float4*>(&ys[tid * 16 + 4]);
  const float4 py2 = *reinterpret_cast<const float4*>(&ys[tid * 16 + 8]);
  const float4 py3 = *reinterpret_cast<const float4*>(&ys[tid * 16 + 12]);
  const float4 pz0 = *reinterpret_cast<const float4*>(&zs[tid * 16 + 0]);
  const float4 pz1 = *reinterpret_cast<const float4*>(&zs[tid * 16 + 4]);
  const float4 pz2 = *reinterpret_cast<const float4*>(&zs[tid * 16 + 8]);
  const float4 pz3 = *reinterpret_cast<const float4*>(&zs[tid * 16 + 12]);
  float4 md0 = make_float4(1e10f, 1e10f, 1e10f, 1e10f);
  float4 md1 = md0, md2 = md0, md3 = md0;
  int far = 0;
  float cx = xs[0], cy = ys[0], cz = zs[0];
  for (int m = 0; m < M_; ++m){
    if (tid == 0) inds_s[m] = far;
    float bv = -1.0f; int bj = 0;
    STEP4(md0, px0, py0, pz0, 0)
    STEP4(md1, px1, py1, pz1, 4)
    STEP4(md2, px2, py2, pz2, 8)
    STEP4(md3, px3, py3, pz3, 12)
    // in-wave max via DPP (VALU, no LDS): result in lane 63
    float wm = bv;
    DPPMAX(wm, 0x111);  // row_shr:1
    DPPMAX(wm, 0x112);  // row_shr:2
    DPPMAX(wm, 0x114);  // row_shr:4
    DPPMAX(wm, 0x118);  // row_shr:8
    DPPMAX(wm, 0x142);  // row_bcast:15
    DPPMAX(wm, 0x143);  // row_bcast:31
    const float wmax = __int_as_float(
        __builtin_amdgcn_readlane(__float_as_int(wm), 63));
    // lowest tied lane = smallest n (lane ascending == n ascending per wave)
    unsigned long long tied = __ballot(bv == wmax);
    const int winlane = (int)__builtin_ctzll(tied);
    const int sl = m & 1;
    if (lane == winlane){
      int wn = tid * 16 + bj;
      sv_[sl][wv] = ((unsigned long long)__float_as_uint(wmax) << 32)
                  | (unsigned)(4095 - wn);     // (4095-n): smaller n wins on tie
    }
    __syncthreads();
    // 4-slot max tree; all pk distinct (distinct indices) => total order
    unsigned long long p0 = sv_[sl][0], p1 = sv_[sl][1], p2 = sv_[sl][2], p3 = sv_[sl][3];
    if (p1 > p0) p0 = p1;
    if (p3 > p2) p2 = p3;
    if (p2 > p0) p0 = p2;
    far = 4095 - (int)(p0 & 0xffffffffu);
    cx = xs[far]; cy = ys[far]; cz = zs[far];   // broadcast LDS reads
  }
  __syncthreads();
  for (int t = tid; t < M_; t += 256){
    int id = inds_s[t];
    size_t o = ((size_t)b * M_ + t) * 3;
    newxyz[o] = xs[id]; newxyz[o + 1] = ys[id]; newxyz[o + 2] = zs[id];
  }
}

// ---------------- phi: per-point layer-0 matmul (no gather) -----------------
__global__ __launch_bounds__(256) void phi_kernel(const float* __restrict__ xyz,
                                                  const float* __restrict__ points,
                                                  const float* __restrict__ W,
                                                  float* __restrict__ phi){
  __shared__ __align__(16) float Wt[67][64];
  __shared__ __align__(16) float ft[67][128];
  const int tid = threadIdx.x, blk = blockIdx.x;
  const int p0 = blk * 128;
  for (int i = tid; i < 67 * 64; i += 256){
    int o = i / 67, c = i - o * 67;
    Wt[c][o] = W[i];
  }
  const int sl = tid >> 1, half = tid & 1;
  const int p = p0 + sl;
  const float* ps = points + (size_t)p * CPTS_ + half * 32;
  #pragma unroll
  for (int j = 0; j < 8; ++j){
    float4 v = *reinterpret_cast<const float4*>(ps + j * 4);
    int c = 3 + half * 32 + j * 4;
    ft[c][sl] = v.x; ft[c + 1][sl] = v.y; ft[c + 2][sl] = v.z; ft[c + 3][sl] = v.w;
  }
  if (half == 0){
    const float* xp = xyz + (size_t)p * 3;
    ft[0][sl] = xp[0]; ft[1][sl] = xp[1]; ft[2][sl] = xp[2];
  }
  __syncthreads();
  const int sg = tid & 31, og = tid >> 5;
  float acc[4][8];
  #pragma unroll
  for (int i = 0; i < 4; ++i)
    #pragma unroll
    for (int o = 0; o < 8; ++o) acc[i][o] = 0.0f;
  #pragma unroll 2
  for (int c = 0; c < 67; ++c){
    float4 f = *reinterpret_cast<const float4*>(&ft[c][sg * 4]);
    float4 w0 = *reinterpret_cast<const float4*>(&Wt[c][og * 8]);
    float4 w1 = *reinterpret_cast<const float4*>(&Wt[c][og * 8 + 4]);
    const float fv[4] = {f.x, f.y, f.z, f.w};
    #pragma unroll
    for (int i = 0; i < 4; ++i){
      acc[i][0] += fv[i] * w0.x; acc[i][1] += fv[i] * w0.y;
      acc[i][2] += fv[i] * w0.z; acc[i][3] += fv[i] * w0.w;
      acc[i][4] += fv[i] * w1.x; acc[i][5] += fv[i] * w1.y;
      acc[i][6] += fv[i] * w1.z; acc[i][7] += fv[i] * w1.w;
    }
  }
  #pragma unroll
  for (int i = 0; i < 4; ++i){
    float* dst = phi + (size_t)(p0 + sg * 4 + i) * 64 + og * 8;
    *reinterpret_cast<float4*>(dst)     = make_float4(acc[i][0], acc[i][1], acc[i][2], acc[i][3]);
    *reinterpret_cast<float4*>(dst + 4) = make_float4(acc[i][4], acc[i][5], acc[i][6], acc[i][7]);
  }
}

// ---------------- Ball query (blocks 0..4095) + psi (blocks 4096..4159) -----
__global__ __launch_bounds__(256) void ballq_psi_kernel(const float* __restrict__ xyz,
                                                        const float* __restrict__ newxyz,
                                                        int* __restrict__ gi,
                                                        float* __restrict__ gif,
                                                        const float* __restrict__ W0,
                                                        float* __restrict__ psi){
  if (blockIdx.x >= 4096){
    const int mi = (blockIdx.x - 4096) * 256 + threadIdx.x;
    const float x = newxyz[(size_t)mi * 3];
    const float y = newxyz[(size_t)mi * 3 + 1];
    const float z = newxyz[(size_t)mi * 3 + 2];
    float* dst = psi + (size_t)mi * 64;
    #pragma unroll
    for (int o4 = 0; o4 < 16; ++o4){
      float v[4];
      #pragma unroll
      for (int e = 0; e < 4; ++e){
        int o = o4 * 4 + e;
        v[e] = fmaf(z, W0[o * 67 + 2], fmaf(y, W0[o * 67 + 1], x * W0[o * 67]));
      }
      *reinterpret_cast<float4*>(dst + o4 * 4) = make_float4(v[0], v[1], v[2], v[3]);
    }
    return;
  }
  const int gw = (blockIdx.x * 256 + threadIdx.x) >> 6;
  const int lane = threadIdx.x & 63;
  const int b = gw >> 10, m = gw & 1023;
  const float* xb = xyz + (size_t)b * N_ * 3;
  const size_t no = (size_t)b * M_ + m;
  const float cx = newxyz[no * 3], cy = newxyz[no * 3 + 1], cz = newxyz[no * 3 + 2];
  const float sm = fmaf(cz, cz, fmaf(cy, cy, cx * cx));
  int total = 0, first_idx = 0; bool havef = false;
  int*   gd = gi  + no * K_;
  float* fd = gif + no * K_;
  for (int ch = 0; ch < 64 && total < K_; ++ch){
    const int n = ch * 64 + lane;
    const float x = xb[n * 3], y = xb[n * 3 + 1], z = xb[n * 3 + 2];
    const float sn = fmaf(z, z, fmaf(y, y, x * x));
    const float dt = fmaf(z, cz, fmaf(y, cy, x * cx));
    float d2 = (sm + sn) - 2.0f * dt;                 // ref: |a|^2+|b|^2-2ab
    float dist = sqrtf(fmaxf(d2, 0.0f));
    bool pred = !(dist > 0.2f);
    unsigned long long mask = __ballot(pred);
    if (!havef && mask){ havef = true; first_idx = ch * 64 + (int)__builtin_ctzll(mask); }
    if (pred){
      int rank = total + (int)__popcll(mask & ((1ull << lane) - 1ull));
      if (rank < K_){ gd[rank] = n; fd[rank] = (float)n; }
    }
    total += (int)__popcll(mask);
  }
  if (total < K_ && lane >= total && lane < K_){ gd[lane] = first_idx; fd[lane] = (float)first_idx; }
}

// ---------------- stats0: BN0 sums over gathered (phi - psi) ----------------
__global__ __launch_bounds__(256) void stats0_kernel(const float* __restrict__ phi,
                                                     const float* __restrict__ psi,
                                                     const int* __restrict__ gi,
                                                     float* __restrict__ part){
  __shared__ int gidx[128];
  __shared__ float psm[4][64];
  const int tid = threadIdx.x, blk = blockIdx.x;
  const size_t s0 = (size_t)blk * 128;
  const int b  = (int)(s0 >> 15);
  const int m0 = ((int)(s0 & 32767)) >> 5;
  if (tid < 128) gidx[tid] = gi[(size_t)b * 32768 + (size_t)m0 * K_ + tid];
  psm[tid >> 6][tid & 63] =
      psi[((size_t)b * M_ + m0 + (tid >> 6)) * 64 + (tid & 63)];
  __syncthreads();
  const int sg = tid & 31, og = tid >> 5;
  const int mi = sg >> 3;
  float sv[8], sq[8];
  #pragma unroll
  for (int o = 0; o < 8; ++o){ sv[o] = 0.f; sq[o] = 0.f; }
  #pragma unroll
  for (int i = 0; i < 4; ++i){
    const int g = gidx[sg * 4 + i];
    const float* gp = phi + ((size_t)b * N_ + g) * 64 + og * 8;
    float4 a0 = *reinterpret_cast<const float4*>(gp);
    float4 a1 = *reinterpret_cast<const float4*>(gp + 4);
    const float pv[8] = {a0.x, a0.y, a0.z, a0.w, a1.x, a1.y, a1.z, a1.w};
    #pragma unroll
    for (int o = 0; o < 8; ++o){
      float v = pv[o] - psm[mi][og * 8 + o];
      sv[o] += v; sq[o] += v * v;
    }
  }
  #pragma unroll
  for (int off = 1; off < 32; off <<= 1){
    #pragma unroll
    for (int o = 0; o < 8; ++o){
      sv[o] += __shfl_xor(sv[o], off);
      sq[o] += __shfl_xor(sq[o], off);
    }
  }
  if (sg == 0){
    #pragma unroll
    for (int o = 0; o < 8; ++o){
      int ch = og * 8 + o;
      part[(size_t)(ch * 2) * 4096 + blk]     = sv[o];
      part[(size_t)(ch * 2 + 1) * 4096 + blk] = sq[o];
    }
  }
}

// ---------------- mlp1 via MFMA (split-bf16, 3-term) — R13-verified ---------
__global__ __launch_bounds__(256) void mlp1_mfma(
    const float* __restrict__ phi, const float* __restrict__ psi,
    const int* __restrict__ gi, const float* __restrict__ bn0,
    const float* __restrict__ W1,
    unsigned short* __restrict__ h1, float* __restrict__ part)
{
  __shared__ unsigned short wsh[64 * 72], wsl[64 * 72];
  __shared__ unsigned short fsh[128 * 72], fsl[128 * 72];
  __shared__ int gidx[128];
  __shared__ float psm[4][64];
  const int tid = threadIdx.x, blk = blockIdx.x;
  const size_t s0 = (size_t)blk * 128;
  const int b  = (int)(s0 >> 15);
  const int m0 = ((int)(s0 & 32767)) >> 5;

  for (int i = tid; i < 64 * 64; i += 256){
    int o = i >> 6, c = i & 63;
    float f = W1[i];
    unsigned hb = f2bf(f);
    float res = f - bf2f((unsigned short)hb);
    wsh[o * 72 + c] = (unsigned short)hb;
    wsl[o * 72 + c] = (unsigned short)f2bf(res);
  }
  if (tid < 128) gidx[tid] = gi[(size_t)b * 32768 + (size_t)m0 * K_ + tid];
  psm[tid >> 6][tid & 63] =
      psi[((size_t)b * M_ + m0 + (tid >> 6)) * 64 + (tid & 63)];
  __syncthreads();
  {
    const int sl = tid >> 1, half = tid & 1;
    const int g = gidx[sl];
    const int mi = sl >> 5;
    const float* gp = phi + ((size_t)b * N_ + g) * 64 + half * 32;
    #pragma unroll
    for (int jj = 0; jj < 4; ++jj){
      float4 v0 = *reinterpret_cast<const float4*>(gp + jj * 8);
      float4 v1 = *reinterpret_cast<const float4*>(gp + jj * 8 + 4);
      const float vv[8] = {v0.x, v0.y, v0.z, v0.w, v1.x, v1.y, v1.z, v1.w};
      ushort8 ph, pl;
      #pragma unroll
      for (int e = 0; e < 8; ++e){
        int c = half * 32 + jj * 8 + e;
        float f = fmaxf((vv[e] - psm[mi][c]) * bn0[c] + bn0[64 + c], 0.0f);
        unsigned hb = f2bf(f);
        float res = f - bf2f((unsigned short)hb);
        ph[e] = (unsigned short)hb;
        pl[e] = (unsigned short)f2bf(res);
      }
      *reinterpret_cast<ushort8*>(&fsh[sl * 72 + half * 32 + jj * 8]) = ph;
      *reinterpret_cast<ushort8*>(&fsl[sl * 72 + half * 32 + jj * 8]) = pl;
    }
  }
  __syncthreads();

  const int l = tid & 63, w = tid >> 6;
  const int col = l & 15, g4 = l >> 4;
  const int ch = w * 16 + col;

  bf16x8 bh[2], bl[2];
  #pragma unroll
  for (int ks = 0; ks < 2; ++ks){
    int a = ch * 72 + ks * 32 + g4 * 8;
    bh[ks] = *reinterpret_cast<const bf16x8*>(&wsh[a]);
    bl[ks] = *reinterpret_cast<const bf16x8*>(&wsl[a]);
  }

  f32x4v acc[8];
  #pragma unroll
  for (int st = 0; st < 8; ++st) acc[st] = (f32x4v){0.f, 0.f, 0.f, 0.f};

  #pragma unroll
  for (int st = 0; st < 8; ++st){
    #pragma unroll
    for (int ks = 0; ks < 2; ++ks){
      int a = (st * 16 + col) * 72 + ks * 32 + g4 * 8;
      bf16x8 ah = *reinterpret_cast<const bf16x8*>(&fsh[a]);
      bf16x8 al = *reinterpret_cast<const bf16x8*>(&fsl[a]);
      acc[st] = __builtin_amdgcn_mfma_f32_16x16x32_bf16(ah, bh[ks], acc[st], 0, 0, 0);
      acc[st] = __builtin_amdgcn_mfma_f32_16x16x32_bf16(ah, bl[ks], acc[st], 0, 0, 0);
      acc[st] = __builtin_amdgcn_mfma_f32_16x16x32_bf16(al, bh[ks], acc[st], 0, 0, 0);
    }
  }

  #pragma unroll
  for (int st = 0; st < 8; ++st){
    size_t sbase = s0 + st * 16 + g4 * 4;
    #pragma unroll
    for (int r = 0; r < 4; ++r)
      h1[(sbase + r) * 64 + ch] = (unsigned short)f2bf(acc[st][r]);
  }

  float sv = 0.f, sq = 0.f;
  #pragma unroll
  for (int st = 0; st < 8; ++st){
    f32x4v a = acc[st];
    float t0 = a[0], t1 = a[1], t2 = a[2], t3 = a[3];
    sv += ((t0 + t1) + t2) + t3;
    sq += ((t0 * t0 + t1 * t1) + t2 * t2) + t3 * t3;
  }
  sv += __shfl_xor(sv, 16); sv += __shfl_xor(sv, 32);
  sq += __shfl_xor(sq, 16); sq += __shfl_xor(sq, 32);
  if (g4 == 0){
    part[(size_t)(ch * 2) * 4096 + blk]     = sv;
    part[(size_t)(ch * 2 + 1) * 4096 + blk] = sq;
  }
}

// ---------------- mlp2 via MFMA (split-bf16, 3-term) — R12-verified ---------
__global__ __launch_bounds__(256) void mlp2_mfma(
    const unsigned short* __restrict__ h1, const float* __restrict__ bn1,
    const float* __restrict__ W2, float* __restrict__ part,
    float* __restrict__ mxmn)
{
  __shared__ unsigned short wsh[128 * 72], wsl[128 * 72];
  __shared__ unsigned short fsh[128 * 72], fsl[128 * 72];
  const int tid = threadIdx.x, blk = blockIdx.x;
  const size_t s0 = (size_t)blk * 128;

  for (int i = tid; i < 128 * 64; i += 256){
    int o = i >> 6, c = i & 63;
    float f = W2[i];
    unsigned hb = f2bf(f);
    float res = f - bf2f((unsigned short)hb);
    wsh[o * 72 + c] = (unsigned short)hb;
    wsl[o * 72 + c] = (unsigned short)f2bf(res);
  }
  {
    const int sl = tid >> 1, c0 = (tid & 1) * 32;
    const unsigned short* hp = h1 + (s0 + sl) * 64 + c0;
    #pragma unroll
    for (int j = 0; j < 4; ++j){
      ushort8 raw = *reinterpret_cast<const ushort8*>(hp + j * 8);
      ushort8 ph, pl;
      #pragma unroll
      for (int e = 0; e < 8; ++e){
        int c = c0 + j * 8 + e;
        float f = fmaxf(bf2f(raw[e]) * bn1[c] + bn1[64 + c], 0.0f);
        unsigned hb = f2bf(f);
        float res = f - bf2f((unsigned short)hb);
        ph[e] = (unsigned short)hb;
        pl[e] = (unsigned short)f2bf(res);
      }
      *reinterpret_cast<ushort8*>(&fsh[sl * 72 + c0 + j * 8]) = ph;
      *reinterpret_cast<ushort8*>(&fsl[sl * 72 + c0 + j * 8]) = pl;
    }
  }
  __syncthreads();

  const int l = tid & 63, w = tid >> 6;
  const int col = l & 15, g = l >> 4;

  bf16x8 bh[2][2], bl[2][2];
  #pragma unroll
  for (int ot = 0; ot < 2; ++ot)
    #pragma unroll
    for (int ks = 0; ks < 2; ++ks){
      int a = (w * 32 + ot * 16 + col) * 72 + ks * 32 + g * 8;
      bh[ot][ks] = *reinterpret_cast<const bf16x8*>(&wsh[a]);
      bl[ot][ks] = *reinterpret_cast<const bf16x8*>(&wsl[a]);
    }

  f32x4v acc[8][2];
  #pragma unroll
  for (int st = 0; st < 8; ++st)
    #pragma unroll
    for (int ot = 0; ot < 2; ++ot)
      acc[st][ot] = (f32x4v){0.f, 0.f, 0.f, 0.f};

  #pragma unroll
  for (int st = 0; st < 8; ++st){
    bf16x8 ah[2], al[2];
    #pragma unroll
    for (int ks = 0; ks < 2; ++ks){
      int a = (st * 16 + col) * 72 + ks * 32 + g * 8;
      ah[ks] = *reinterpret_cast<const bf16x8*>(&fsh[a]);
      al[ks] = *reinterpret_cast<const bf16x8*>(&fsl[a]);
    }
    #pragma unroll
    for (int ot = 0; ot < 2; ++ot){
      #pragma unroll
      for (int ks = 0; ks < 2; ++ks){
        acc[st][ot] = __builtin_amdgcn_mfma_f32_16x16x32_bf16(ah[ks], bh[ot][ks], acc[st][ot], 0, 0, 0);
        acc[st][ot] = __builtin_amdgcn_mfma_f32_16x16x32_bf16(ah[ks], bl[ot][ks], acc[st][ot], 0, 0, 0);
        acc[st][ot] = __builtin_amdgcn_mfma_f32_16x16x32_bf16(al[ks], bh[ot][ks], acc[st][ot], 0, 0, 0);
      }
    }
  }

  #pragma unroll
  for (int ot = 0; ot < 2; ++ot){
    const int ch = w * 32 + ot * 16 + col;
    float sv = 0.f, sq = 0.f;
    float mxm[4], mnm[4];
    #pragma unroll
    for (int j = 0; j < 4; ++j){ mxm[j] = -1e30f; mnm[j] = 1e30f; }
    #pragma unroll
    for (int st = 0; st < 8; ++st){
      f32x4v a = acc[st][ot];
      float t0 = a[0], t1 = a[1], t2 = a[2], t3 = a[3];
      sv += ((t0 + t1) + t2) + t3;
      sq += ((t0 * t0 + t1 * t1) + t2 * t2) + t3 * t3;
      float tmx = fmaxf(fmaxf(t0, t1), fmaxf(t2, t3));
      float tmn = fminf(fminf(t0, t1), fminf(t2, t3));
      mxm[st >> 1] = fmaxf(mxm[st >> 1], tmx);
      mnm[st >> 1] = fminf(mnm[st >> 1], tmn);
    }
    sv += __shfl_xor(sv, 16); sv += __shfl_xor(sv, 32);
    sq += __shfl_xor(sq, 16); sq += __shfl_xor(sq, 32);
    #pragma unroll
    for (int j = 0; j < 4; ++j){
      mxm[j] = fmaxf(mxm[j], __shfl_xor(mxm[j], 16));
      mxm[j] = fmaxf(mxm[j], __shfl_xor(mxm[j], 32));
      mnm[j] = fminf(mnm[j], __shfl_xor(mnm[j], 16));
      mnm[j] = fminf(mnm[j], __shfl_xor(mnm[j], 32));
    }
    if (g == 0){
      part[(size_t)(ch * 2) * 4096 + blk]     = sv;
      part[(size_t)(ch * 2 + 1) * 4096 + blk] = sq;
      #pragma unroll
      for (int j = 0; j < 4; ++j){
        size_t mf = (s0 >> 5) + j;
        mxmn[mf * 128 + ch]          = mxm[j];
        mxmn[MF_TOT + mf * 128 + ch] = mnm[j];
      }
    }
  }
}

// ---------------- BN stats reduce + scale/shift -----------------------------
__global__ __launch_bounds__(256) void reduce_stats(const float* __restrict__ part,
                                                    const float* __restrict__ g,
                                                    const float* __restrict__ bb,
                                                    float* __restrict__ bn, int cout){
  const int ch = blockIdx.x, tid = threadIdx.x;
  float s = 0.f, q = 0.f;
  const float* ps = part + (size_t)(ch * 2) * 4096;
  const float* pq = part + (size_t)(ch * 2 + 1) * 4096;
  for (int i = tid; i < 4096; i += 256){ s += ps[i]; q += pq[i]; }
  #pragma unroll
  for (int off = 1; off < 64; off <<= 1){ s += __shfl_xor(s, off); q += __shfl_xor(q, off); }
  __shared__ float as_[4], aq_[4];
  if ((tid & 63) == 0){ as_[tid >> 6] = s; aq_[tid >> 6] = q; }
  __syncthreads();
  if (tid == 0){
    float S = as_[0] + as_[1] + as_[2] + as_[3];
    float Q = aq_[0] + aq_[1] + aq_[2] + aq_[3];
    const float cnt = 524288.0f;
    float mean = S / cnt;
    float var  = Q / cnt - mean * mean;
    float sc = g[ch] / sqrtf(var + 1e-5f);
    bn[ch] = sc;
    bn[cout + ch] = bb[ch] - mean * sc;
  }
}

// ---------------- finish: out = relu(max(a*mx+sh, a*mn+sh)) -----------------
__global__ __launch_bounds__(256) void bn_minmax_finish(const float* __restrict__ mxmn,
                                                        const float* __restrict__ bn2,
                                                        float* __restrict__ out){
  const int i = blockIdx.x * 256 + threadIdx.x;
  const int ch = i & 127;
  const float a = bn2[ch], sh = bn2[128 + ch];
  const float mx = mxmn[i], mn = mxmn[MF_TOT + i];
  out[i] = fmaxf(fmaxf(mx * a + sh, mn * a + sh), 0.0f);
}

extern "C" void kernel_launch(void* const* d_in, const int* in_sizes, int n_in,
                              void* d_out, int out_size, void* d_ws, size_t ws_size,
                              hipStream_t stream){
  (void)in_sizes; (void)n_in; (void)out_size; (void)ws_size;
  const float* xyz    = (const float*)d_in[0];
  const float* points = (const float*)d_in[1];
  const float* W0 = (const float*)d_in[2];
  const float* g0 = (const float*)d_in[3];
  const float* b0 = (const float*)d_in[4];
  const float* W1 = (const float*)d_in[5];
  const float* g1 = (const float*)d_in[6];
  const float* b1 = (const float*)d_in[7];
  const float* W2 = (const float*)d_in[8];
  const float* g2 = (const float*)d_in[9];
  const float* b2 = (const float*)d_in[10];

  float* out = (float*)d_out;
  float* o_newxyz = out;
  float* o_newpts = out + (size_t)B_ * M_ * 3;
  float* o_gind   = out + (size_t)B_ * M_ * 3 + (size_t)B_ * M_ * 128;

  char* ws = (char*)d_ws;
  int*   gi   = (int*)(ws + 0);                          // 2 MB
  float* part = (float*)(ws + (2ull << 20));             // 4 MB
  float* bn0  = (float*)(ws + (6ull << 20));
  float* bn1  = (float*)(ws + (6ull << 20) + 1024);
  float* bn2  = (float*)(ws + (6ull << 20) + 2048);
  float* phi  = (float*)(ws + (8ull << 20));             // 16 MB
  float* psi  = (float*)(ws + (24ull << 20));            // 4 MB
  unsigned short* h1 = (unsigned short*)(ws + (28ull << 20));   // 64 MB
  float* mxmn = (float*)(ws + (92ull << 20));            // 16 MB

  phi_kernel<<<512, 256, 0, stream>>>(xyz, points, W0, phi);
  fps_kernel<<<16, 256, 0, stream>>>(xyz, o_newxyz);
  ballq_psi_kernel<<<4160, 256, 0, stream>>>(xyz, o_newxyz, gi, o_gind, W0, psi);

  stats0_kernel<<<4096, 256, 0, stream>>>(phi, psi, gi, part);
  reduce_stats<<<64, 256, 0, stream>>>(part, g0, b0, bn0, 64);

  mlp1_mfma<<<4096, 256, 0, stream>>>(phi, psi, gi, bn0, W1, h1, part);
  reduce_stats<<<64, 256, 0, stream>>>(part, g1, b1, bn1, 64);

  mlp2_mfma<<<4096, 256, 0, stream>>>(h1, bn1, W2, part, mxmn);
  reduce_stats<<<128, 256, 0, stream>>>(part, g2, b2, bn2, 128);
  bn_minmax_finish<<<MF_TOT / 256, 256, 0, stream>>>(mxmn, bn2, o_newpts);
}